// Round 2
// baseline (1437.784 us; speedup 1.0000x reference)
//
#include <hip/hip_runtime.h>
#include <math.h>

#define TB 8
#define TC 128
#define TP 96
#define TD 128
#define TH 8
#define TG 512

#define DOT4(va, vb) ((va).x*(vb).x + (va).y*(vb).y + (va).z*(vb).z + (va).w*(vb).w)

// LayerNorm over rows held in LDS (width-132-padded, D=128 valid cols).
// 4 lanes per row, shfl-reduce within the 4-lane group.
template <int NROWS>
__device__ __forceinline__ void ln_rows(float (*src)[132], float (*dst)[132],
                                        int tid, const float* lng, const float* lnb)
{
  if (tid < NROWS * 4) {
    int r = tid >> 2, sub = tid & 3;
    float s = 0.f, s2 = 0.f;
    #pragma unroll
    for (int j = 0; j < 32; ++j) {
      float x = src[r][sub * 32 + j];
      s += x; s2 += x * x;
    }
    s  += __shfl_xor(s, 1);  s  += __shfl_xor(s, 2);
    s2 += __shfl_xor(s2, 1); s2 += __shfl_xor(s2, 2);
    float mu = s * (1.f / 128.f);
    float rs = rsqrtf(s2 * (1.f / 128.f) - mu * mu + 1e-5f);
    #pragma unroll
    for (int j = 0; j < 32; ++j) {
      int d = sub * 32 + j;
      dst[r][d] = (src[r][d] - mu) * rs * lng[d] + lnb[d];
    }
  }
}

// ---------------------------------------------------------------------------
// K1: time messages. One block per (b,c). Writes m_t to out (STORE).
// ---------------------------------------------------------------------------
__global__ __launch_bounds__(512) void k_time(
    const float* __restrict__ qz, const float* __restrict__ tu,
    const float* __restrict__ tv, const float* __restrict__ lng,
    const float* __restrict__ lnb, float* __restrict__ out)
{
  __shared__ float zn[96][132];
  __shared__ float quA[96][132];   // all-head u-proj; reused as attn-sum later
  __shared__ float qvA[96][132];   // all-head v-proj

  const int tid = threadIdx.x;
  const int b = blockIdx.x >> 7;
  const int c = blockIdx.x & 127;
  const size_t base = (size_t)(b * TC + c) * (TP * TD);

  // load qz[b,c,:,:] and layernorm it
  #pragma unroll
  for (int i = 0; i < 6; ++i) {
    int idx4 = tid + i * 512;
    int p = idx4 >> 5;
    int d0 = (idx4 & 31) << 2;
    *(float4*)&zn[p][d0] = *(const float4*)(qz + base + (size_t)p * TD + d0);
  }
  __syncthreads();
  ln_rows<96>(zn, zn, tid, lng, lnb);
  __syncthreads();

  // head projections: outputs [96 p][256 o]; o<128 -> quA (time_u), else qvA (time_v)
  {
    const int og = tid & 31, pg = tid >> 5;
    const int o0 = og << 3, p0 = pg * 6;
    const float* W = ((o0 < 128) ? tu : tv) + (size_t)b * (TD * TD);
    const int ow = o0 & 127;
    float acc[6][8];
    #pragma unroll
    for (int i = 0; i < 6; ++i)
      #pragma unroll
      for (int j = 0; j < 8; ++j) acc[i][j] = 0.f;
    for (int d4 = 0; d4 < TD; d4 += 4) {
      float4 a[6];
      #pragma unroll
      for (int i = 0; i < 6; ++i) a[i] = *(const float4*)&zn[p0 + i][d4];
      #pragma unroll
      for (int j = 0; j < 8; ++j) {
        float4 w = *(const float4*)(W + (size_t)(ow + j) * TD + d4);
        #pragma unroll
        for (int i = 0; i < 6; ++i) acc[i][j] += DOT4(a[i], w);
      }
    }
    float (*dst)[132];
    if (o0 < 128) dst = quA; else dst = qvA;
    #pragma unroll
    for (int i = 0; i < 6; ++i)
      #pragma unroll
      for (int j = 0; j < 8; ++j) dst[p0 + i][ow + j] = acc[i][j];
  }
  __syncthreads();

  // per-head scores + softmax + head-sum, fully in registers.
  // lane owns 3 p-rows x 6 q-cols; a row p is spread over 16 consecutive lanes.
  const int qg2 = tid & 15, pg2 = tid >> 4;
  const int q0 = qg2 * 6, p0s = pg2 * 3;
  float asum[3][6];
  #pragma unroll
  for (int i = 0; i < 3; ++i)
    #pragma unroll
    for (int j = 0; j < 6; ++j) asum[i][j] = 0.f;

  for (int h = 0; h < TH; ++h) {
    const int hb = h * 16;
    float s[3][6];
    #pragma unroll
    for (int i = 0; i < 3; ++i)
      #pragma unroll
      for (int j = 0; j < 6; ++j) s[i][j] = 0.f;
    #pragma unroll
    for (int r4 = 0; r4 < 16; r4 += 4) {
      float4 a[3], v[6];
      #pragma unroll
      for (int i = 0; i < 3; ++i) a[i] = *(const float4*)&quA[p0s + i][hb + r4];
      #pragma unroll
      for (int j = 0; j < 6; ++j) v[j] = *(const float4*)&qvA[q0 + j][hb + r4];
      #pragma unroll
      for (int i = 0; i < 3; ++i)
        #pragma unroll
        for (int j = 0; j < 6; ++j) s[i][j] += DOT4(a[i], v[j]);
    }
    #pragma unroll
    for (int i = 0; i < 3; ++i) {
      float m = -1e30f;
      #pragma unroll
      for (int j = 0; j < 6; ++j) { s[i][j] *= 0.25f; m = fmaxf(m, s[i][j]); }
      m = fmaxf(m, __shfl_xor(m, 1));
      m = fmaxf(m, __shfl_xor(m, 2));
      m = fmaxf(m, __shfl_xor(m, 4));
      m = fmaxf(m, __shfl_xor(m, 8));
      float e[6], tot = 0.f;
      #pragma unroll
      for (int j = 0; j < 6; ++j) { e[j] = __expf(s[i][j] - m); tot += e[j]; }
      tot += __shfl_xor(tot, 1);
      tot += __shfl_xor(tot, 2);
      tot += __shfl_xor(tot, 4);
      tot += __shfl_xor(tot, 8);
      float inv = 1.f / tot;
      #pragma unroll
      for (int j = 0; j < 6; ++j) asum[i][j] += e[j] * inv;
    }
  }
  __syncthreads();   // all reads of quA done before overwrite
  #pragma unroll
  for (int i = 0; i < 3; ++i)
    #pragma unroll
    for (int j = 0; j < 6; ++j) quA[p0s + i][q0 + j] = asum[i][j];
  __syncthreads();

  // apply: m_t[p][d] = (1/8) * sum_q asum[p][q] * zn[q][d]
  {
    const int dg = tid & 31, pg = tid >> 5;
    const int d0 = dg << 2, p0 = pg * 6;
    float4 accv[6];
    #pragma unroll
    for (int i = 0; i < 6; ++i) accv[i] = make_float4(0.f, 0.f, 0.f, 0.f);
    for (int q4 = 0; q4 < 96; q4 += 4) {
      float4 z[4];
      #pragma unroll
      for (int k = 0; k < 4; ++k) z[k] = *(const float4*)&zn[q4 + k][d0];
      #pragma unroll
      for (int i = 0; i < 6; ++i) {
        float4 sv = *(const float4*)&quA[p0 + i][q4];
        accv[i].x += sv.x*z[0].x + sv.y*z[1].x + sv.z*z[2].x + sv.w*z[3].x;
        accv[i].y += sv.x*z[0].y + sv.y*z[1].y + sv.z*z[2].y + sv.w*z[3].y;
        accv[i].z += sv.x*z[0].z + sv.y*z[1].z + sv.z*z[2].z + sv.w*z[3].z;
        accv[i].w += sv.x*z[0].w + sv.y*z[1].w + sv.z*z[2].w + sv.w*z[3].w;
      }
    }
    #pragma unroll
    for (int i = 0; i < 6; ++i) {
      float4 r;
      r.x = accv[i].x * 0.125f; r.y = accv[i].y * 0.125f;
      r.z = accv[i].z * 0.125f; r.w = accv[i].w * 0.125f;
      *(float4*)(out + base + (size_t)(p0 + i) * TD + d0) = r;
    }
  }
}

// ---------------------------------------------------------------------------
// K2: channel messages. One block per (b,p). ADDS m_c into out.
// ---------------------------------------------------------------------------
__global__ __launch_bounds__(512) void k_channel(
    const float* __restrict__ qz, const float* __restrict__ cu,
    const float* __restrict__ cv, const float* __restrict__ lng,
    const float* __restrict__ lnb, float* __restrict__ out)
{
  __shared__ float patch[128][132];  // qz_n[b,:,p,:]
  __shared__ float quH[128][68];     // 4 heads worth (64 cols)
  __shared__ float qvH[128][68];

  const int tid = threadIdx.x;
  const int b = blockIdx.x / TP;
  const int p = blockIdx.x - b * TP;
  const size_t bbase = (size_t)b * (TC * TP * TD);

  #pragma unroll
  for (int i = 0; i < 8; ++i) {
    int idx4 = tid + i * 512;
    int cc = idx4 >> 5;
    int d0 = (idx4 & 31) << 2;
    *(float4*)&patch[cc][d0] =
        *(const float4*)(qz + bbase + ((size_t)cc * TP + p) * TD + d0);
  }
  __syncthreads();
  ln_rows<128>(patch, patch, tid, lng, lnb);

  // lane owns 4 c-rows x 8 dd-cols (dd = dg2 + 16*j); row spread over 16 lanes
  const int dg2 = tid & 15, cg2 = tid >> 4;
  const int c0s = cg2 * 4;
  float asum[4][8];
  #pragma unroll
  for (int i = 0; i < 4; ++i)
    #pragma unroll
    for (int j = 0; j < 8; ++j) asum[i][j] = 0.f;

  for (int hp = 0; hp < 2; ++hp) {
    __syncthreads();   // also covers LN->first use
    // projections for heads hp*4 .. hp*4+3 (64 cols per matrix)
    {
      const int og = tid & 31, cg = tid >> 5;
      const int o0 = og * 4, c0 = cg * 8;
      const int mat = o0 >> 6;
      const int rr0 = o0 & 63;
      const float* W = ((mat == 0) ? cu : cv) + (size_t)b * (TD * TD) + (size_t)(hp * 64) * TD;
      float acc[8][4];
      #pragma unroll
      for (int i = 0; i < 8; ++i)
        #pragma unroll
        for (int j = 0; j < 4; ++j) acc[i][j] = 0.f;
      for (int d4 = 0; d4 < TD; d4 += 4) {
        float4 a[8];
        #pragma unroll
        for (int i = 0; i < 8; ++i) a[i] = *(const float4*)&patch[c0 + i][d4];
        #pragma unroll
        for (int j = 0; j < 4; ++j) {
          float4 w = *(const float4*)(W + (size_t)(rr0 + j) * TD + d4);
          #pragma unroll
          for (int i = 0; i < 8; ++i) acc[i][j] += DOT4(a[i], w);
        }
      }
      float (*dst)[68];
      if (mat == 0) dst = quH; else dst = qvH;
      #pragma unroll
      for (int i = 0; i < 8; ++i)
        #pragma unroll
        for (int j = 0; j < 4; ++j) dst[c0 + i][rr0 + j] = acc[i][j];
    }
    __syncthreads();
    for (int hh = 0; hh < 4; ++hh) {
      const int rb = hh * 16;
      float s[4][8];
      #pragma unroll
      for (int i = 0; i < 4; ++i)
        #pragma unroll
        for (int j = 0; j < 8; ++j) s[i][j] = 0.f;
      #pragma unroll
      for (int r4 = 0; r4 < 16; r4 += 4) {
        float4 a[4], v[8];
        #pragma unroll
        for (int i = 0; i < 4; ++i) a[i] = *(const float4*)&quH[c0s + i][rb + r4];
        #pragma unroll
        for (int j = 0; j < 8; ++j) v[j] = *(const float4*)&qvH[dg2 + 16 * j][rb + r4];
        #pragma unroll
        for (int i = 0; i < 4; ++i)
          #pragma unroll
          for (int j = 0; j < 8; ++j) s[i][j] += DOT4(a[i], v[j]);
      }
      #pragma unroll
      for (int i = 0; i < 4; ++i) {
        float m = -1e30f;
        #pragma unroll
        for (int j = 0; j < 8; ++j) { s[i][j] *= 0.25f; m = fmaxf(m, s[i][j]); }
        m = fmaxf(m, __shfl_xor(m, 1));
        m = fmaxf(m, __shfl_xor(m, 2));
        m = fmaxf(m, __shfl_xor(m, 4));
        m = fmaxf(m, __shfl_xor(m, 8));
        float e[8], tot = 0.f;
        #pragma unroll
        for (int j = 0; j < 8; ++j) { e[j] = __expf(s[i][j] - m); tot += e[j]; }
        tot += __shfl_xor(tot, 1);
        tot += __shfl_xor(tot, 2);
        tot += __shfl_xor(tot, 4);
        tot += __shfl_xor(tot, 8);
        float inv = 1.f / tot;
        #pragma unroll
        for (int j = 0; j < 8; ++j) asum[i][j] += e[j] * inv;
      }
    }
  }
  // m_c[b,c,p,dd] = mean_h(attn)[c,dd] * qz_n[b,c,p,dd] ; add into out
  #pragma unroll
  for (int i = 0; i < 4; ++i) {
    int cc = c0s + i;
    const size_t rowa = bbase + ((size_t)cc * TP + p) * TD;
    #pragma unroll
    for (int j = 0; j < 8; ++j) {
      int dd = dg2 + 16 * j;
      out[rowa + dd] += asum[i][j] * 0.125f * patch[cc][dd];
    }
  }
}

// ---------------------------------------------------------------------------
// K3: topic messages. One block per 64 rows of one batch. ADDS m_g into out.
// Single sweep over binary tiles: unnormalized accumulate + row-sum, scale at end.
// ---------------------------------------------------------------------------
__global__ __launch_bounds__(256) void k_topic(
    const float* __restrict__ qz, const float* __restrict__ bin,
    const float* __restrict__ lng, const float* __restrict__ lnb,
    float* __restrict__ out)
{
  __shared__ float znT[64][132];
  __shared__ float bt[128][132];
  __shared__ float qgt[64][132];
  __shared__ float rsumL[64];

  const int tid = threadIdx.x;
  const int b = blockIdx.x / 192;
  const int rt = blockIdx.x - b * 192;
  const size_t row0 = (size_t)b * (TC * TP) + (size_t)rt * 64;
  const float* binb = bin + (size_t)b * (TG * TD);

  #pragma unroll
  for (int i = 0; i < 8; ++i) {
    int idx4 = tid + i * 256;
    int r = idx4 >> 5;
    int d0 = (idx4 & 31) << 2;
    *(float4*)&znT[r][d0] = *(const float4*)(qz + (row0 + r) * TD + d0);
  }
  __syncthreads();
  ln_rows<64>(znT, znT, tid, lng, lnb);

  const int gg2 = tid & 31, rg2 = tid >> 5;
  const int r0 = rg2 * 8;
  const int d0m = gg2 * 4;
  float4 macc[8];
  #pragma unroll
  for (int i = 0; i < 8; ++i) macc[i] = make_float4(0.f, 0.f, 0.f, 0.f);
  float rsum_reg = 0.f;
  const int rs_r = tid >> 2, rs_sub = tid & 3;

  for (int gt = 0; gt < 4; ++gt) {
    __syncthreads();   // guard bt/qgt reuse (also covers LN on first iter)
    #pragma unroll
    for (int i = 0; i < 16; ++i) {
      int idx4 = tid + i * 256;
      int gg = idx4 >> 5;
      int d0 = (idx4 & 31) << 2;
      *(float4*)&bt[gg][d0] =
          *(const float4*)(binb + ((size_t)(gt * 128 + gg)) * TD + d0);
    }
    __syncthreads();
    // qg = relu(zn @ bt^T); lane tile: 8 rows x 4 g (g = gg2 + 32*j)
    {
      float acc[8][4];
      #pragma unroll
      for (int i = 0; i < 8; ++i)
        #pragma unroll
        for (int j = 0; j < 4; ++j) acc[i][j] = 0.f;
      for (int d4 = 0; d4 < TD; d4 += 4) {
        float4 a[8];
        #pragma unroll
        for (int i = 0; i < 8; ++i) a[i] = *(const float4*)&znT[r0 + i][d4];
        #pragma unroll
        for (int j = 0; j < 4; ++j) {
          float4 w = *(const float4*)&bt[gg2 + 32 * j][d4];
          #pragma unroll
          for (int i = 0; i < 8; ++i) acc[i][j] += DOT4(a[i], w);
        }
      }
      #pragma unroll
      for (int i = 0; i < 8; ++i)
        #pragma unroll
        for (int j = 0; j < 4; ++j)
          qgt[r0 + i][gg2 + 32 * j] = fmaxf(acc[i][j], 0.f);
    }
    __syncthreads();
    // row-sum partials (for L1 normalization)
    {
      float s = 0.f;
      #pragma unroll
      for (int j = 0; j < 32; ++j) s += qgt[rs_r][rs_sub * 32 + j];
      s += __shfl_xor(s, 1); s += __shfl_xor(s, 2);
      if (rs_sub == 0) rsum_reg += s;
    }
    // accumulate unnormalized m_g: lane tile 8 rows x 4 d
    for (int g4 = 0; g4 < 128; g4 += 4) {
      float4 btv[4];
      #pragma unroll
      for (int k = 0; k < 4; ++k) btv[k] = *(const float4*)&bt[g4 + k][d0m];
      #pragma unroll
      for (int i = 0; i < 8; ++i) {
        float4 q4 = *(const float4*)&qgt[r0 + i][g4];
        macc[i].x += q4.x*btv[0].x + q4.y*btv[1].x + q4.z*btv[2].x + q4.w*btv[3].x;
        macc[i].y += q4.x*btv[0].y + q4.y*btv[1].y + q4.z*btv[2].y + q4.w*btv[3].y;
        macc[i].z += q4.x*btv[0].z + q4.y*btv[1].z + q4.z*btv[2].z + q4.w*btv[3].z;
        macc[i].w += q4.x*btv[0].w + q4.y*btv[1].w + q4.z*btv[2].w + q4.w*btv[3].w;
      }
    }
  }
  if (rs_sub == 0) rsumL[rs_r] = rsum_reg;
  __syncthreads();
  #pragma unroll
  for (int i = 0; i < 8; ++i) {
    float inv = 1.f / fmaxf(rsumL[r0 + i], 1e-6f);
    float* oa = out + (row0 + r0 + i) * TD + d0m;
    float4 o4 = *(float4*)oa;
    o4.x += macc[i].x * inv;
    o4.y += macc[i].y * inv;
    o4.z += macc[i].z * inv;
    o4.w += macc[i].w * inv;
    *(float4*)oa = o4;
  }
}

// ---------------------------------------------------------------------------
// K4: combine + MLP. One block per 64 rows.
// out currently holds m_t+m_c+m_g; compute qz_new = 0.5*(unary+acc+qz), LN,
// gelu(h@w1^T+b1)@w2^T+b2, residual; overwrite out.
// ---------------------------------------------------------------------------
__global__ __launch_bounds__(256) void k_final(
    const float* __restrict__ qz, const float* __restrict__ unary,
    const float* __restrict__ lng, const float* __restrict__ lnb,
    const float* __restrict__ w1, const float* __restrict__ b1,
    const float* __restrict__ w2, const float* __restrict__ b2,
    float* __restrict__ out)
{
  __shared__ float zmid[64][132];
  __shared__ float hbuf[64][132];
  __shared__ float wbuf[128][132];

  const int tid = threadIdx.x;
  const size_t row0 = (size_t)blockIdx.x * 64;

  #pragma unroll
  for (int i = 0; i < 8; ++i) {
    int idx4 = tid + i * 256;
    int r = idx4 >> 5;
    int d0 = (idx4 & 31) << 2;
    size_t a = (row0 + r) * TD + d0;
    float4 u4 = *(const float4*)(unary + a);
    float4 q4 = *(const float4*)(qz + a);
    float4 m4 = *(const float4*)(out + a);
    float4 z;
    z.x = 0.5f * (u4.x + m4.x + q4.x);
    z.y = 0.5f * (u4.y + m4.y + q4.y);
    z.z = 0.5f * (u4.z + m4.z + q4.z);
    z.w = 0.5f * (u4.w + m4.w + q4.w);
    *(float4*)&zmid[r][d0] = z;
  }
  __syncthreads();
  ln_rows<64>(zmid, hbuf, tid, lng, lnb);
  #pragma unroll
  for (int i = 0; i < 16; ++i) {
    int idx4 = tid + i * 256;
    int o = idx4 >> 5;
    int d0 = (idx4 & 31) << 2;
    *(float4*)&wbuf[o][d0] = *(const float4*)(w1 + (size_t)o * TD + d0);
  }
  __syncthreads();

  const int og = tid & 31, rg = tid >> 5;
  const int r0 = rg * 8;
  float acc[8][4];
  #pragma unroll
  for (int i = 0; i < 8; ++i)
    #pragma unroll
    for (int j = 0; j < 4; ++j) acc[i][j] = 0.f;
  for (int d4 = 0; d4 < TD; d4 += 4) {
    float4 a[8];
    #pragma unroll
    for (int i = 0; i < 8; ++i) a[i] = *(const float4*)&hbuf[r0 + i][d4];
    #pragma unroll
    for (int j = 0; j < 4; ++j) {
      float4 w = *(const float4*)&wbuf[og + 32 * j][d4];
      #pragma unroll
      for (int i = 0; i < 8; ++i) acc[i][j] += DOT4(a[i], w);
    }
  }
  float gel[8][4];
  #pragma unroll
  for (int j = 0; j < 4; ++j) {
    float bj = b1[og + 32 * j];
    #pragma unroll
    for (int i = 0; i < 8; ++i) {
      float x = acc[i][j] + bj;
      gel[i][j] = 0.5f * x * (1.f + erff(x * 0.70710678118654752f));
    }
  }
  __syncthreads();   // all GEMM1 reads of hbuf done
  #pragma unroll
  for (int i = 0; i < 8; ++i)
    #pragma unroll
    for (int j = 0; j < 4; ++j) hbuf[r0 + i][og + 32 * j] = gel[i][j];
  #pragma unroll
  for (int i = 0; i < 16; ++i) {
    int idx4 = tid + i * 256;
    int o = idx4 >> 5;
    int d0 = (idx4 & 31) << 2;
    *(float4*)&wbuf[o][d0] = *(const float4*)(w2 + (size_t)o * TD + d0);
  }
  __syncthreads();

  float acc2[8][4];
  #pragma unroll
  for (int i = 0; i < 8; ++i)
    #pragma unroll
    for (int j = 0; j < 4; ++j) acc2[i][j] = 0.f;
  for (int d4 = 0; d4 < TD; d4 += 4) {
    float4 a[8];
    #pragma unroll
    for (int i = 0; i < 8; ++i) a[i] = *(const float4*)&hbuf[r0 + i][d4];
    #pragma unroll
    for (int j = 0; j < 4; ++j) {
      float4 w = *(const float4*)&wbuf[og + 32 * j][d4];
      #pragma unroll
      for (int i = 0; i < 8; ++i) acc2[i][j] += DOT4(a[i], w);
    }
  }
  #pragma unroll
  for (int j = 0; j < 4; ++j) {
    int o = og + 32 * j;
    float bj = b2[o];
    #pragma unroll
    for (int i = 0; i < 8; ++i) {
      out[(row0 + r0 + i) * TD + o] = zmid[r0 + i][o] + acc2[i][j] + bj;
    }
  }
}

// ---------------------------------------------------------------------------
extern "C" void kernel_launch(void* const* d_in, const int* in_sizes, int n_in,
                              void* d_out, int out_size, void* d_ws, size_t ws_size,
                              hipStream_t stream) {
  (void)in_sizes; (void)n_in; (void)out_size; (void)d_ws; (void)ws_size;
  const float* qz      = (const float*)d_in[0];
  const float* unary   = (const float*)d_in[1];
  const float* time_u  = (const float*)d_in[2];
  const float* time_v  = (const float*)d_in[3];
  const float* chan_u  = (const float*)d_in[4];
  const float* chan_v  = (const float*)d_in[5];
  const float* topic   = (const float*)d_in[6];
  const float* ln_g    = (const float*)d_in[7];
  const float* ln_b    = (const float*)d_in[8];
  const float* w1      = (const float*)d_in[9];
  const float* b1      = (const float*)d_in[10];
  const float* w2      = (const float*)d_in[11];
  const float* b2      = (const float*)d_in[12];
  float* out = (float*)d_out;

  k_time   <<<dim3(TB * TC), dim3(512), 0, stream>>>(qz, time_u, time_v, ln_g, ln_b, out);
  k_channel<<<dim3(TB * TP), dim3(512), 0, stream>>>(qz, chan_u, chan_v, ln_g, ln_b, out);
  k_topic  <<<dim3(TB * 192), dim3(256), 0, stream>>>(qz, topic, ln_g, ln_b, out);
  k_final  <<<dim3(1536), dim3(256), 0, stream>>>(qz, unary, ln_g, ln_b, w1, b1, w2, b2, out);
}

// Round 4
// 1039.544 us; speedup vs baseline: 1.3831x; 1.3831x over previous
//
#include <hip/hip_runtime.h>
#include <math.h>

#define TB 8
#define TC 128
#define TP 96
#define TD 128
#define TH 8
#define TG 512

#define DOT4(va, vb) ((va).x*(vb).x + (va).y*(vb).y + (va).z*(vb).z + (va).w*(vb).w)

typedef __attribute__((ext_vector_type(8))) short  bf16x8_t;
typedef __attribute__((ext_vector_type(8))) unsigned short u16x8_t;
typedef __attribute__((ext_vector_type(4))) float  f32x4_t;

__device__ __forceinline__ unsigned short f2bf(float f) {
  unsigned u = __float_as_uint(f);
  unsigned r = (u + 0x7fffu + ((u >> 16) & 1u)) >> 16;
  return (unsigned short)r;
}

// LayerNorm over rows held in LDS (width-132-padded, D=128 valid cols).
template <int NROWS>
__device__ __forceinline__ void ln_rows(float (*src)[132], float (*dst)[132],
                                        int tid, const float* lng, const float* lnb)
{
  if (tid < NROWS * 4) {
    int r = tid >> 2, sub = tid & 3;
    float s = 0.f, s2 = 0.f;
    #pragma unroll
    for (int j = 0; j < 32; ++j) {
      float x = src[r][sub * 32 + j];
      s += x; s2 += x * x;
    }
    s  += __shfl_xor(s, 1);  s  += __shfl_xor(s, 2);
    s2 += __shfl_xor(s2, 1); s2 += __shfl_xor(s2, 2);
    float mu = s * (1.f / 128.f);
    float rs = rsqrtf(s2 * (1.f / 128.f) - mu * mu + 1e-5f);
    #pragma unroll
    for (int j = 0; j < 32; ++j) {
      int d = sub * 32 + j;
      dst[r][d] = (src[r][d] - mu) * rs * lng[d] + lnb[d];
    }
  }
}

// ---------------------------------------------------------------------------
// K0: prep — convert topic_binary to bf16 in both layouts.
// binB[b][g][d], binT[b][d][g]. Grid: 64 blocks (8 batches x 8 g-tiles of 64).
// ---------------------------------------------------------------------------
__global__ __launch_bounds__(256) void k_prep(
    const float* __restrict__ bin, unsigned short* __restrict__ binB,
    unsigned short* __restrict__ binT)
{
  __shared__ unsigned short tile[64][132];
  const int tid = threadIdx.x;
  const int b = blockIdx.x >> 3;
  const int g0 = (blockIdx.x & 7) * 64;
  const size_t bb = (size_t)b * (TG * TD);

  #pragma unroll
  for (int i = 0; i < 8; ++i) {
    int idx4 = tid + i * 256;            // 2048 float4 = 64x128
    int g = idx4 >> 5;
    int d0 = (idx4 & 31) << 2;
    float4 v = *(const float4*)(bin + bb + (size_t)(g0 + g) * TD + d0);
    ushort4 h;
    h.x = f2bf(v.x); h.y = f2bf(v.y); h.z = f2bf(v.z); h.w = f2bf(v.w);
    *(ushort4*)(binB + bb + (size_t)(g0 + g) * TD + d0) = h;
    tile[g][d0] = h.x; tile[g][d0+1] = h.y; tile[g][d0+2] = h.z; tile[g][d0+3] = h.w;
  }
  __syncthreads();
  // transposed writes: thread -> (d, half); 32 contiguous g per write-run
  const int d = tid >> 1, half = tid & 1;
  unsigned short* dst = binT + (size_t)b * (TD * TG) + (size_t)d * TG + g0 + half * 32;
  #pragma unroll
  for (int i = 0; i < 8; ++i) {
    ushort4 o;
    o.x = tile[half*32 + 4*i + 0][d];
    o.y = tile[half*32 + 4*i + 1][d];
    o.z = tile[half*32 + 4*i + 2][d];
    o.w = tile[half*32 + 4*i + 3][d];
    *(ushort4*)(dst + 4*i) = o;
  }
}

// ---------------------------------------------------------------------------
// K1: time messages. One block per (b,c). Writes m_t to out (STORE).
// ---------------------------------------------------------------------------
__global__ __launch_bounds__(512) void k_time(
    const float* __restrict__ qz, const float* __restrict__ tu,
    const float* __restrict__ tv, const float* __restrict__ lng,
    const float* __restrict__ lnb, float* __restrict__ out)
{
  __shared__ float zn[96][132];
  __shared__ float quA[96][132];
  __shared__ float qvA[96][132];

  const int tid = threadIdx.x;
  const int b = blockIdx.x >> 7;
  const int c = blockIdx.x & 127;
  const size_t base = (size_t)(b * TC + c) * (TP * TD);

  #pragma unroll
  for (int i = 0; i < 6; ++i) {
    int idx4 = tid + i * 512;
    int p = idx4 >> 5;
    int d0 = (idx4 & 31) << 2;
    *(float4*)&zn[p][d0] = *(const float4*)(qz + base + (size_t)p * TD + d0);
  }
  __syncthreads();
  ln_rows<96>(zn, zn, tid, lng, lnb);
  __syncthreads();

  {
    const int og = tid & 31, pg = tid >> 5;
    const int o0 = og << 3, p0 = pg * 6;
    const float* W = ((o0 < 128) ? tu : tv) + (size_t)b * (TD * TD);
    const int ow = o0 & 127;
    float acc[6][8];
    #pragma unroll
    for (int i = 0; i < 6; ++i)
      #pragma unroll
      for (int j = 0; j < 8; ++j) acc[i][j] = 0.f;
    for (int d4 = 0; d4 < TD; d4 += 4) {
      float4 a[6];
      #pragma unroll
      for (int i = 0; i < 6; ++i) a[i] = *(const float4*)&zn[p0 + i][d4];
      #pragma unroll
      for (int j = 0; j < 8; ++j) {
        float4 w = *(const float4*)(W + (size_t)(ow + j) * TD + d4);
        #pragma unroll
        for (int i = 0; i < 6; ++i) acc[i][j] += DOT4(a[i], w);
      }
    }
    float (*dst)[132];
    if (o0 < 128) dst = quA; else dst = qvA;
    #pragma unroll
    for (int i = 0; i < 6; ++i)
      #pragma unroll
      for (int j = 0; j < 8; ++j) dst[p0 + i][ow + j] = acc[i][j];
  }
  __syncthreads();

  const int qg2 = tid & 15, pg2 = tid >> 4;
  const int q0 = qg2 * 6, p0s = pg2 * 3;
  float asum[3][6];
  #pragma unroll
  for (int i = 0; i < 3; ++i)
    #pragma unroll
    for (int j = 0; j < 6; ++j) asum[i][j] = 0.f;

  for (int h = 0; h < TH; ++h) {
    const int hb = h * 16;
    float s[3][6];
    #pragma unroll
    for (int i = 0; i < 3; ++i)
      #pragma unroll
      for (int j = 0; j < 6; ++j) s[i][j] = 0.f;
    #pragma unroll
    for (int r4 = 0; r4 < 16; r4 += 4) {
      float4 a[3], v[6];
      #pragma unroll
      for (int i = 0; i < 3; ++i) a[i] = *(const float4*)&quA[p0s + i][hb + r4];
      #pragma unroll
      for (int j = 0; j < 6; ++j) v[j] = *(const float4*)&qvA[q0 + j][hb + r4];
      #pragma unroll
      for (int i = 0; i < 3; ++i)
        #pragma unroll
        for (int j = 0; j < 6; ++j) s[i][j] += DOT4(a[i], v[j]);
    }
    #pragma unroll
    for (int i = 0; i < 3; ++i) {
      float m = -1e30f;
      #pragma unroll
      for (int j = 0; j < 6; ++j) { s[i][j] *= 0.25f; m = fmaxf(m, s[i][j]); }
      m = fmaxf(m, __shfl_xor(m, 1));
      m = fmaxf(m, __shfl_xor(m, 2));
      m = fmaxf(m, __shfl_xor(m, 4));
      m = fmaxf(m, __shfl_xor(m, 8));
      float e[6], tot = 0.f;
      #pragma unroll
      for (int j = 0; j < 6; ++j) { e[j] = __expf(s[i][j] - m); tot += e[j]; }
      tot += __shfl_xor(tot, 1);
      tot += __shfl_xor(tot, 2);
      tot += __shfl_xor(tot, 4);
      tot += __shfl_xor(tot, 8);
      float inv = 1.f / tot;
      #pragma unroll
      for (int j = 0; j < 6; ++j) asum[i][j] += e[j] * inv;
    }
  }
  __syncthreads();
  #pragma unroll
  for (int i = 0; i < 3; ++i)
    #pragma unroll
    for (int j = 0; j < 6; ++j) quA[p0s + i][q0 + j] = asum[i][j];
  __syncthreads();

  {
    const int dg = tid & 31, pg = tid >> 5;
    const int d0 = dg << 2, p0 = pg * 6;
    float4 accv[6];
    #pragma unroll
    for (int i = 0; i < 6; ++i) accv[i] = make_float4(0.f, 0.f, 0.f, 0.f);
    for (int q4 = 0; q4 < 96; q4 += 4) {
      float4 z[4];
      #pragma unroll
      for (int k = 0; k < 4; ++k) z[k] = *(const float4*)&zn[q4 + k][d0];
      #pragma unroll
      for (int i = 0; i < 6; ++i) {
        float4 sv = *(const float4*)&quA[p0 + i][q4];
        accv[i].x += sv.x*z[0].x + sv.y*z[1].x + sv.z*z[2].x + sv.w*z[3].x;
        accv[i].y += sv.x*z[0].y + sv.y*z[1].y + sv.z*z[2].y + sv.w*z[3].y;
        accv[i].z += sv.x*z[0].z + sv.y*z[1].z + sv.z*z[2].z + sv.w*z[3].z;
        accv[i].w += sv.x*z[0].w + sv.y*z[1].w + sv.z*z[2].w + sv.w*z[3].w;
      }
    }
    #pragma unroll
    for (int i = 0; i < 6; ++i) {
      float4 r;
      r.x = accv[i].x * 0.125f; r.y = accv[i].y * 0.125f;
      r.z = accv[i].z * 0.125f; r.w = accv[i].w * 0.125f;
      *(float4*)(out + base + (size_t)(p0 + i) * TD + d0) = r;
    }
  }
}

// ---------------------------------------------------------------------------
// K2: channel messages. One block per (b,p). ADDS m_c into out.
// ---------------------------------------------------------------------------
__global__ __launch_bounds__(512) void k_channel(
    const float* __restrict__ qz, const float* __restrict__ cu,
    const float* __restrict__ cv, const float* __restrict__ lng,
    const float* __restrict__ lnb, float* __restrict__ out)
{
  __shared__ float patch[128][132];
  __shared__ float quH[128][68];
  __shared__ float qvH[128][68];

  const int tid = threadIdx.x;
  const int b = blockIdx.x / TP;
  const int p = blockIdx.x - b * TP;
  const size_t bbase = (size_t)b * (TC * TP * TD);

  #pragma unroll
  for (int i = 0; i < 8; ++i) {
    int idx4 = tid + i * 512;
    int cc = idx4 >> 5;
    int d0 = (idx4 & 31) << 2;
    *(float4*)&patch[cc][d0] =
        *(const float4*)(qz + bbase + ((size_t)cc * TP + p) * TD + d0);
  }
  __syncthreads();
  ln_rows<128>(patch, patch, tid, lng, lnb);

  const int dg2 = tid & 15, cg2 = tid >> 4;
  const int c0s = cg2 * 4;
  float asum[4][8];
  #pragma unroll
  for (int i = 0; i < 4; ++i)
    #pragma unroll
    for (int j = 0; j < 8; ++j) asum[i][j] = 0.f;

  for (int hp = 0; hp < 2; ++hp) {
    __syncthreads();
    {
      const int og = tid & 31, cg = tid >> 5;
      const int o0 = og * 4, c0 = cg * 8;
      const int mat = o0 >> 6;
      const int rr0 = o0 & 63;
      const float* W = ((mat == 0) ? cu : cv) + (size_t)b * (TD * TD) + (size_t)(hp * 64) * TD;
      float acc[8][4];
      #pragma unroll
      for (int i = 0; i < 8; ++i)
        #pragma unroll
        for (int j = 0; j < 4; ++j) acc[i][j] = 0.f;
      for (int d4 = 0; d4 < TD; d4 += 4) {
        float4 a[8];
        #pragma unroll
        for (int i = 0; i < 8; ++i) a[i] = *(const float4*)&patch[c0 + i][d4];
        #pragma unroll
        for (int j = 0; j < 4; ++j) {
          float4 w = *(const float4*)(W + (size_t)(rr0 + j) * TD + d4);
          #pragma unroll
          for (int i = 0; i < 8; ++i) acc[i][j] += DOT4(a[i], w);
        }
      }
      float (*dst)[68];
      if (mat == 0) dst = quH; else dst = qvH;
      #pragma unroll
      for (int i = 0; i < 8; ++i)
        #pragma unroll
        for (int j = 0; j < 4; ++j) dst[c0 + i][rr0 + j] = acc[i][j];
    }
    __syncthreads();
    for (int hh = 0; hh < 4; ++hh) {
      const int rb = hh * 16;
      float s[4][8];
      #pragma unroll
      for (int i = 0; i < 4; ++i)
        #pragma unroll
        for (int j = 0; j < 8; ++j) s[i][j] = 0.f;
      #pragma unroll
      for (int r4 = 0; r4 < 16; r4 += 4) {
        float4 a[4], v[8];
        #pragma unroll
        for (int i = 0; i < 4; ++i) a[i] = *(const float4*)&quH[c0s + i][rb + r4];
        #pragma unroll
        for (int j = 0; j < 8; ++j) v[j] = *(const float4*)&qvH[dg2 + 16 * j][rb + r4];
        #pragma unroll
        for (int i = 0; i < 4; ++i)
          #pragma unroll
          for (int j = 0; j < 8; ++j) s[i][j] += DOT4(a[i], v[j]);
      }
      #pragma unroll
      for (int i = 0; i < 4; ++i) {
        float m = -1e30f;
        #pragma unroll
        for (int j = 0; j < 8; ++j) { s[i][j] *= 0.25f; m = fmaxf(m, s[i][j]); }
        m = fmaxf(m, __shfl_xor(m, 1));
        m = fmaxf(m, __shfl_xor(m, 2));
        m = fmaxf(m, __shfl_xor(m, 4));
        m = fmaxf(m, __shfl_xor(m, 8));
        float e[8], tot = 0.f;
        #pragma unroll
        for (int j = 0; j < 8; ++j) { e[j] = __expf(s[i][j] - m); tot += e[j]; }
        tot += __shfl_xor(tot, 1);
        tot += __shfl_xor(tot, 2);
        tot += __shfl_xor(tot, 4);
        tot += __shfl_xor(tot, 8);
        float inv = 1.f / tot;
        #pragma unroll
        for (int j = 0; j < 8; ++j) asum[i][j] += e[j] * inv;
      }
    }
  }
  #pragma unroll
  for (int i = 0; i < 4; ++i) {
    int cc = c0s + i;
    const size_t rowa = bbase + ((size_t)cc * TP + p) * TD;
    #pragma unroll
    for (int j = 0; j < 8; ++j) {
      int dd = dg2 + 16 * j;
      out[rowa + dd] += asum[i][j] * 0.125f * patch[cc][dd];
    }
  }
}

// ---------------------------------------------------------------------------
// K3: topic messages, bf16 MFMA. One block per 128 rows (512 thr, 8 waves).
// Wave w: wr=w>>2 selects 64-row half, wc=w&3 selects 32-col quarter.
// GEMM1: s = zn @ bt^T (contract d) -> relu -> qg (bf16, LDS) + fp32 rowsum.
// GEMM2: macc += qg @ bt (contract g) via pre-transposed btT.
// L1-normalize at the end, += into out.
// ---------------------------------------------------------------------------
__global__ __launch_bounds__(512) void k_topic(
    const float* __restrict__ qz, const unsigned short* __restrict__ binB,
    const unsigned short* __restrict__ binT, const float* __restrict__ lng,
    const float* __restrict__ lnb, float* __restrict__ out)
{
  __shared__ unsigned short zn [128][136];
  __shared__ unsigned short bt [128][136];
  __shared__ unsigned short btT[128][136];
  __shared__ unsigned short qg [128][136];
  __shared__ float rsum[4][128];

  const int tid = threadIdx.x;
  const int b = blockIdx.x / 96;
  const size_t row0 = (size_t)blockIdx.x * 128;
  const unsigned short* binBb = binB + (size_t)b * (TG * TD);
  const unsigned short* binTb = binT + (size_t)b * (TD * TG);

  // --- LayerNorm qz rows -> bf16 zn ---
  {
    const int r = tid >> 2, sub = tid & 3;
    float x[32];
    float s = 0.f, s2 = 0.f;
    #pragma unroll
    for (int i = 0; i < 8; ++i) {
      float4 v = *(const float4*)(qz + (row0 + r) * TD + sub * 32 + i * 4);
      x[i*4+0] = v.x; x[i*4+1] = v.y; x[i*4+2] = v.z; x[i*4+3] = v.w;
      s += v.x + v.y + v.z + v.w;
      s2 += v.x*v.x + v.y*v.y + v.z*v.z + v.w*v.w;
    }
    s  += __shfl_xor(s, 1);  s  += __shfl_xor(s, 2);
    s2 += __shfl_xor(s2, 1); s2 += __shfl_xor(s2, 2);
    float mu = s * (1.f / 128.f);
    float rs = rsqrtf(s2 * (1.f / 128.f) - mu * mu + 1e-5f);
    #pragma unroll
    for (int j0 = 0; j0 < 32; j0 += 8) {
      u16x8_t v;
      #pragma unroll
      for (int j = 0; j < 8; ++j) {
        int d = sub * 32 + j0 + j;
        v[j] = f2bf((x[j0+j] - mu) * rs * lng[d] + lnb[d]);
      }
      *(u16x8_t*)&zn[r][sub * 32 + j0] = v;
    }
  }

  const int l = tid & 63;
  const int w = tid >> 6;
  const int wr = w >> 2;         // 0..1: 64-row half
  const int wc = w & 3;          // 0..3: 32-col quarter
  const int ln16 = l & 15, lg16 = l >> 4;

  f32x4_t macc[4][2];
  #pragma unroll
  for (int mi = 0; mi < 4; ++mi)
    #pragma unroll
    for (int ni = 0; ni < 2; ++ni) macc[mi][ni] = (f32x4_t)0.f;
  float rs_acc[4][4];
  #pragma unroll
  for (int mi = 0; mi < 4; ++mi)
    #pragma unroll
    for (int rg = 0; rg < 4; ++rg) rs_acc[mi][rg] = 0.f;

  for (int gt = 0; gt < 4; ++gt) {
    if (gt) __syncthreads();     // protect bt/btT/qg from previous iter readers
    // --- stage bt (binB tile) and btT (binT tile) ---
    {
      const int row = tid >> 2, seg = tid & 3;
      const unsigned short* gsrc = binBb + (size_t)(gt * 128 + row) * TD + seg * 32;
      #pragma unroll
      for (int i = 0; i < 4; ++i)
        *(u16x8_t*)&bt[row][seg * 32 + i * 8] = *(const u16x8_t*)(gsrc + i * 8);
      const unsigned short* tsrc = binTb + (size_t)row * TG + gt * 128 + seg * 32;
      #pragma unroll
      for (int i = 0; i < 4; ++i)
        *(u16x8_t*)&btT[row][seg * 32 + i * 8] = *(const u16x8_t*)(tsrc + i * 8);
    }
    __syncthreads();

    // --- GEMM1: s[128r][128g] = zn @ bt^T, relu, -> qg + rowsum ---
    {
      bf16x8_t B1[2][4];
      #pragma unroll
      for (int ni = 0; ni < 2; ++ni)
        #pragma unroll
        for (int k = 0; k < 4; ++k)
          B1[ni][k] = *(const bf16x8_t*)&bt[wc*32 + ni*16 + ln16][k*32 + lg16*8];
      #pragma unroll
      for (int mi = 0; mi < 4; ++mi) {
        const int r0 = wr*64 + mi*16;
        bf16x8_t A[4];
        #pragma unroll
        for (int k = 0; k < 4; ++k)
          A[k] = *(const bf16x8_t*)&zn[r0 + ln16][k*32 + lg16*8];
        #pragma unroll
        for (int ni = 0; ni < 2; ++ni) {
          f32x4_t acc = (f32x4_t)0.f;
          #pragma unroll
          for (int k = 0; k < 4; ++k)
            acc = __builtin_amdgcn_mfma_f32_16x16x32_bf16(A[k], B1[ni][k], acc, 0, 0, 0);
          #pragma unroll
          for (int rg = 0; rg < 4; ++rg) {
            float v = fmaxf(acc[rg], 0.f);
            rs_acc[mi][rg] += v;
            qg[r0 + lg16*4 + rg][wc*32 + ni*16 + ln16] = f2bf(v);
          }
        }
      }
    }
    __syncthreads();

    // --- GEMM2: macc += qg @ bt  (B from btT, contract g) ---
    {
      bf16x8_t B2[2][4];
      #pragma unroll
      for (int ni = 0; ni < 2; ++ni)
        #pragma unroll
        for (int k = 0; k < 4; ++k)
          B2[ni][k] = *(const bf16x8_t*)&btT[wc*32 + ni*16 + ln16][k*32 + lg16*8];
      #pragma unroll
      for (int mi = 0; mi < 4; ++mi) {
        const int r0 = wr*64 + mi*16;
        bf16x8_t A2[4];
        #pragma unroll
        for (int k = 0; k < 4; ++k)
          A2[k] = *(const bf16x8_t*)&qg[r0 + ln16][k*32 + lg16*8];
        #pragma unroll
        for (int ni = 0; ni < 2; ++ni)
          #pragma unroll
          for (int k = 0; k < 4; ++k)
            macc[mi][ni] = __builtin_amdgcn_mfma_f32_16x16x32_bf16(A2[k], B2[ni][k], macc[mi][ni], 0, 0, 0);
      }
    }
  }

  // --- rowsum reduce across lanes (same row = same lg16) then across wc ---
  #pragma unroll
  for (int mi = 0; mi < 4; ++mi)
    #pragma unroll
    for (int rg = 0; rg < 4; ++rg) {
      float s = rs_acc[mi][rg];
      s += __shfl_xor(s, 1); s += __shfl_xor(s, 2);
      s += __shfl_xor(s, 4); s += __shfl_xor(s, 8);
      rs_acc[mi][rg] = s;
    }
  if (ln16 == 0) {
    #pragma unroll
    for (int mi = 0; mi < 4; ++mi)
      #pragma unroll
      for (int rg = 0; rg < 4; ++rg)
        rsum[wc][wr*64 + mi*16 + lg16*4 + rg] = rs_acc[mi][rg];
  }
  __syncthreads();

  // --- normalize + accumulate into out ---
  #pragma unroll
  for (int mi = 0; mi < 4; ++mi) {
    #pragma unroll
    for (int rg = 0; rg < 4; ++rg) {
      const int r = wr*64 + mi*16 + lg16*4 + rg;
      float tot = rsum[0][r] + rsum[1][r] + rsum[2][r] + rsum[3][r];
      float inv = 1.f / fmaxf(tot, 1e-6f);
      #pragma unroll
      for (int ni = 0; ni < 2; ++ni) {
        int d = wc*32 + ni*16 + ln16;
        out[(row0 + r) * TD + d] += macc[mi][ni][rg] * inv;
      }
    }
  }
}

// ---------------------------------------------------------------------------
// K4: combine + MLP. One block per 64 rows.
// ---------------------------------------------------------------------------
__global__ __launch_bounds__(256) void k_final(
    const float* __restrict__ qz, const float* __restrict__ unary,
    const float* __restrict__ lng, const float* __restrict__ lnb,
    const float* __restrict__ w1, const float* __restrict__ b1,
    const float* __restrict__ w2, const float* __restrict__ b2,
    float* __restrict__ out)
{
  __shared__ float zmid[64][132];
  __shared__ float hbuf[64][132];
  __shared__ float wbuf[128][132];

  const int tid = threadIdx.x;
  const size_t row0 = (size_t)blockIdx.x * 64;

  #pragma unroll
  for (int i = 0; i < 8; ++i) {
    int idx4 = tid + i * 256;
    int r = idx4 >> 5;
    int d0 = (idx4 & 31) << 2;
    size_t a = (row0 + r) * TD + d0;
    float4 u4 = *(const float4*)(unary + a);
    float4 q4 = *(const float4*)(qz + a);
    float4 m4 = *(const float4*)(out + a);
    float4 z;
    z.x = 0.5f * (u4.x + m4.x + q4.x);
    z.y = 0.5f * (u4.y + m4.y + q4.y);
    z.z = 0.5f * (u4.z + m4.z + q4.z);
    z.w = 0.5f * (u4.w + m4.w + q4.w);
    *(float4*)&zmid[r][d0] = z;
  }
  __syncthreads();
  ln_rows<64>(zmid, hbuf, tid, lng, lnb);
  #pragma unroll
  for (int i = 0; i < 16; ++i) {
    int idx4 = tid + i * 256;
    int o = idx4 >> 5;
    int d0 = (idx4 & 31) << 2;
    *(float4*)&wbuf[o][d0] = *(const float4*)(w1 + (size_t)o * TD + d0);
  }
  __syncthreads();

  const int og = tid & 31, rg = tid >> 5;
  const int r0 = rg * 8;
  float acc[8][4];
  #pragma unroll
  for (int i = 0; i < 8; ++i)
    #pragma unroll
    for (int j = 0; j < 4; ++j) acc[i][j] = 0.f;
  for (int d4 = 0; d4 < TD; d4 += 4) {
    float4 a[8];
    #pragma unroll
    for (int i = 0; i < 8; ++i) a[i] = *(const float4*)&hbuf[r0 + i][d4];
    #pragma unroll
    for (int j = 0; j < 4; ++j) {
      float4 w = *(const float4*)&wbuf[og + 32 * j][d4];
      #pragma unroll
      for (int i = 0; i < 8; ++i) acc[i][j] += DOT4(a[i], w);
    }
  }
  float gel[8][4];
  #pragma unroll
  for (int j = 0; j < 4; ++j) {
    float bj = b1[og + 32 * j];
    #pragma unroll
    for (int i = 0; i < 8; ++i) {
      float x = acc[i][j] + bj;
      gel[i][j] = 0.5f * x * (1.f + erff(x * 0.70710678118654752f));
    }
  }
  __syncthreads();
  #pragma unroll
  for (int i = 0; i < 8; ++i)
    #pragma unroll
    for (int j = 0; j < 4; ++j) hbuf[r0 + i][og + 32 * j] = gel[i][j];
  #pragma unroll
  for (int i = 0; i < 16; ++i) {
    int idx4 = tid + i * 256;
    int o = idx4 >> 5;
    int d0 = (idx4 & 31) << 2;
    *(float4*)&wbuf[o][d0] = *(const float4*)(w2 + (size_t)o * TD + d0);
  }
  __syncthreads();

  float acc2[8][4];
  #pragma unroll
  for (int i = 0; i < 8; ++i)
    #pragma unroll
    for (int j = 0; j < 4; ++j) acc2[i][j] = 0.f;
  for (int d4 = 0; d4 < TD; d4 += 4) {
    float4 a[8];
    #pragma unroll
    for (int i = 0; i < 8; ++i) a[i] = *(const float4*)&hbuf[r0 + i][d4];
    #pragma unroll
    for (int j = 0; j < 4; ++j) {
      float4 w = *(const float4*)&wbuf[og + 32 * j][d4];
      #pragma unroll
      for (int i = 0; i < 8; ++i) acc2[i][j] += DOT4(a[i], w);
    }
  }
  #pragma unroll
  for (int j = 0; j < 4; ++j) {
    int o = og + 32 * j;
    float bj = b2[o];
    #pragma unroll
    for (int i = 0; i < 8; ++i) {
      out[(row0 + r0 + i) * TD + o] = zmid[r0 + i][o] + acc2[i][j] + bj;
    }
  }
}

// ---------------------------------------------------------------------------
extern "C" void kernel_launch(void* const* d_in, const int* in_sizes, int n_in,
                              void* d_out, int out_size, void* d_ws, size_t ws_size,
                              hipStream_t stream) {
  (void)in_sizes; (void)n_in; (void)out_size; (void)ws_size;
  const float* qz      = (const float*)d_in[0];
  const float* unary   = (const float*)d_in[1];
  const float* time_u  = (const float*)d_in[2];
  const float* time_v  = (const float*)d_in[3];
  const float* chan_u  = (const float*)d_in[4];
  const float* chan_v  = (const float*)d_in[5];
  const float* topic   = (const float*)d_in[6];
  const float* ln_g    = (const float*)d_in[7];
  const float* ln_b    = (const float*)d_in[8];
  const float* w1      = (const float*)d_in[9];
  const float* b1      = (const float*)d_in[10];
  const float* w2      = (const float*)d_in[11];
  const float* b2      = (const float*)d_in[12];
  float* out = (float*)d_out;

  unsigned short* binB = (unsigned short*)d_ws;                 // 8*512*128 bf16
  unsigned short* binT = binB + (size_t)TB * TG * TD;           // 8*128*512 bf16

  k_prep   <<<dim3(64), dim3(256), 0, stream>>>(topic, binB, binT);
  k_time   <<<dim3(TB * TC), dim3(512), 0, stream>>>(qz, time_u, time_v, ln_g, ln_b, out);
  k_channel<<<dim3(TB * TP), dim3(512), 0, stream>>>(qz, chan_u, chan_v, ln_g, ln_b, out);
  k_topic  <<<dim3(TB * 96), dim3(512), 0, stream>>>(qz, binB, binT, ln_g, ln_b, out);
  k_final  <<<dim3(1536), dim3(256), 0, stream>>>(qz, unary, ln_g, ln_b, w1, b1, w2, b2, out);
}

// Round 5
// 593.610 us; speedup vs baseline: 2.4221x; 1.7512x over previous
//
#include <hip/hip_runtime.h>
#include <math.h>

#define TB 8
#define TC 128
#define TP 96
#define TD 128
#define TH 8
#define TG 512

#define DOT4(va, vb) ((va).x*(vb).x + (va).y*(vb).y + (va).z*(vb).z + (va).w*(vb).w)

typedef __attribute__((ext_vector_type(8))) short  bf16x8_t;
typedef __attribute__((ext_vector_type(8))) unsigned short u16x8_t;
typedef __attribute__((ext_vector_type(4))) float  f32x4_t;

__device__ __forceinline__ unsigned short f2bf(float f) {
  unsigned u = __float_as_uint(f);
  unsigned r = (u + 0x7fffu + ((u >> 16) & 1u)) >> 16;
  return (unsigned short)r;
}
__device__ __forceinline__ float bf2f(unsigned short h) {
  return __uint_as_float((unsigned)h << 16);
}

// LayerNorm over rows held in LDS (fp32, width-132-padded). Used by k_final.
template <int NROWS>
__device__ __forceinline__ void ln_rows(float (*src)[132], float (*dst)[132],
                                        int tid, const float* lng, const float* lnb)
{
  if (tid < NROWS * 4) {
    int r = tid >> 2, sub = tid & 3;
    float s = 0.f, s2 = 0.f;
    #pragma unroll
    for (int j = 0; j < 32; ++j) {
      float x = src[r][sub * 32 + j];
      s += x; s2 += x * x;
    }
    s  += __shfl_xor(s, 1);  s  += __shfl_xor(s, 2);
    s2 += __shfl_xor(s2, 1); s2 += __shfl_xor(s2, 2);
    float mu = s * (1.f / 128.f);
    float rs = rsqrtf(s2 * (1.f / 128.f) - mu * mu + 1e-5f);
    #pragma unroll
    for (int j = 0; j < 32; ++j) {
      int d = sub * 32 + j;
      dst[r][d] = (src[r][d] - mu) * rs * lng[d] + lnb[d];
    }
  }
}

// ---------------------------------------------------------------------------
// K0a: prep — convert topic_binary to bf16 in both layouts.
// ---------------------------------------------------------------------------
__global__ __launch_bounds__(256) void k_prep(
    const float* __restrict__ bin, unsigned short* __restrict__ binB,
    unsigned short* __restrict__ binT)
{
  __shared__ unsigned short tile[64][132];
  const int tid = threadIdx.x;
  const int b = blockIdx.x >> 3;
  const int g0 = (blockIdx.x & 7) * 64;
  const size_t bb = (size_t)b * (TG * TD);

  #pragma unroll
  for (int i = 0; i < 8; ++i) {
    int idx4 = tid + i * 256;
    int g = idx4 >> 5;
    int d0 = (idx4 & 31) << 2;
    float4 v = *(const float4*)(bin + bb + (size_t)(g0 + g) * TD + d0);
    ushort4 h;
    h.x = f2bf(v.x); h.y = f2bf(v.y); h.z = f2bf(v.z); h.w = f2bf(v.w);
    *(ushort4*)(binB + bb + (size_t)(g0 + g) * TD + d0) = h;
    tile[g][d0] = h.x; tile[g][d0+1] = h.y; tile[g][d0+2] = h.z; tile[g][d0+3] = h.w;
  }
  __syncthreads();
  const int d = tid >> 1, half = tid & 1;
  unsigned short* dst = binT + (size_t)b * (TD * TG) + (size_t)d * TG + g0 + half * 32;
  #pragma unroll
  for (int i = 0; i < 8; ++i) {
    ushort4 o;
    o.x = tile[half*32 + 4*i + 0][d];
    o.y = tile[half*32 + 4*i + 1][d];
    o.z = tile[half*32 + 4*i + 2][d];
    o.w = tile[half*32 + 4*i + 3][d];
    *(ushort4*)(dst + 4*i) = o;
  }
}

// ---------------------------------------------------------------------------
// K0b: prep — convert the 4 per-batch attention weight mats to bf16.
// 512 blocks x 256 thr; each block converts 1024 consecutive floats.
// ---------------------------------------------------------------------------
__global__ __launch_bounds__(256) void k_prepw(
    const float* __restrict__ tu, const float* __restrict__ tv,
    const float* __restrict__ cu, const float* __restrict__ cv,
    unsigned short* __restrict__ wTu, unsigned short* __restrict__ wTv,
    unsigned short* __restrict__ wCu, unsigned short* __restrict__ wCv)
{
  const int m = blockIdx.x >> 7;
  const int off = (blockIdx.x & 127) * 1024 + threadIdx.x * 4;
  const float* src = (m == 0) ? tu : (m == 1) ? tv : (m == 2) ? cu : cv;
  unsigned short* dst = (m == 0) ? wTu : (m == 1) ? wTv : (m == 2) ? wCu : wCv;
  float4 v = *(const float4*)(src + off);
  ushort4 h;
  h.x = f2bf(v.x); h.y = f2bf(v.y); h.z = f2bf(v.z); h.w = f2bf(v.w);
  *(ushort4*)(dst + off) = h;
}

// ---------------------------------------------------------------------------
// K1: time messages, full MFMA. One block per (b,c), 384 thr (6 waves).
// Wave w = p-tile. proj: qu/qv = zn @ W^T. scores: T[e][p] per head
// (K=16 zero-padded to 32), softmax over e in registers, head-sum -> asum.
// apply: m_t = asum @ zn via znT. STORES m_t to out.
// ---------------------------------------------------------------------------
__global__ __launch_bounds__(384) void k_time(
    const float* __restrict__ qz, const unsigned short* __restrict__ wTu,
    const unsigned short* __restrict__ wTv, const float* __restrict__ lng,
    const float* __restrict__ lnb, float* __restrict__ out)
{
  __shared__ unsigned short zn [96][136];
  __shared__ unsigned short znT[128][104];
  __shared__ unsigned short qu [96][136];
  __shared__ unsigned short qv [96][136];

  const int tid = threadIdx.x;
  const int b = blockIdx.x >> 7;
  const int c = blockIdx.x & 127;
  const size_t base = (size_t)(b * TC + c) * (TP * TD);

  // --- LN -> zn (bf16) + znT (bf16, transposed) ---
  {
    const int r = tid >> 2, sub = tid & 3;   // 96 rows x 4 lanes
    float x[32];
    float s = 0.f, s2 = 0.f;
    #pragma unroll
    for (int i = 0; i < 8; ++i) {
      float4 v = *(const float4*)(qz + base + (size_t)r * TD + sub * 32 + i * 4);
      x[i*4+0] = v.x; x[i*4+1] = v.y; x[i*4+2] = v.z; x[i*4+3] = v.w;
      s += v.x + v.y + v.z + v.w;
      s2 += v.x*v.x + v.y*v.y + v.z*v.z + v.w*v.w;
    }
    s  += __shfl_xor(s, 1);  s  += __shfl_xor(s, 2);
    s2 += __shfl_xor(s2, 1); s2 += __shfl_xor(s2, 2);
    float mu = s * (1.f / 128.f);
    float rs = rsqrtf(s2 * (1.f / 128.f) - mu * mu + 1e-5f);
    unsigned short hv[32];
    #pragma unroll
    for (int j = 0; j < 32; ++j) {
      int d = sub * 32 + j;
      hv[j] = f2bf((x[j] - mu) * rs * lng[d] + lnb[d]);
    }
    #pragma unroll
    for (int j0 = 0; j0 < 32; j0 += 8) {
      u16x8_t v;
      #pragma unroll
      for (int j = 0; j < 8; ++j) v[j] = hv[j0 + j];
      *(u16x8_t*)&zn[r][sub * 32 + j0] = v;
    }
    #pragma unroll
    for (int j = 0; j < 32; ++j) znT[sub * 32 + j][r] = hv[j];
  }
  __syncthreads();

  const int l = tid & 63, w = tid >> 6;      // w = p-tile 0..5
  const int ln16 = l & 15, lg16 = l >> 4;
  const int prow = w * 16 + ln16;

  // --- proj: qu[p][o] = sum_d zn[p][d] W[o][d] ---
  {
    bf16x8_t A[4];
    #pragma unroll
    for (int k = 0; k < 4; ++k)
      A[k] = *(const bf16x8_t*)&zn[prow][k*32 + lg16*8];
    #pragma unroll
    for (int m = 0; m < 2; ++m) {
      const unsigned short* W = ((m == 0) ? wTu : wTv) + (size_t)b * 16384;
      #pragma unroll
      for (int ot = 0; ot < 8; ++ot) {
        bf16x8_t Bf[4];
        #pragma unroll
        for (int k = 0; k < 4; ++k)
          Bf[k] = *(const bf16x8_t*)(W + (size_t)(ot*16 + ln16) * 128 + k*32 + lg16*8);
        f32x4_t acc = (f32x4_t)0.f;
        #pragma unroll
        for (int k = 0; k < 4; ++k)
          acc = __builtin_amdgcn_mfma_f32_16x16x32_bf16(A[k], Bf[k], acc, 0, 0, 0);
        unsigned short (*dst)[136] = (m == 0) ? qu : qv;
        #pragma unroll
        for (int rg = 0; rg < 4; ++rg)
          dst[w*16 + lg16*4 + rg][ot*16 + ln16] = f2bf(acc[rg]);
      }
    }
  }
  __syncthreads();

  // --- scores (transposed) + softmax over e + head-sum ---
  f32x4_t asumT[6];
  #pragma unroll
  for (int et = 0; et < 6; ++et) asumT[et] = (f32x4_t)0.f;
  const bf16x8_t zfrag = (bf16x8_t)(short)0;
  const int koff = (lg16 & 1) * 8;   // safe col offset; lg16>=2 lanes zeroed
  for (int h = 0; h < TH; ++h) {
    bf16x8_t Bq = *(const bf16x8_t*)&qu[prow][h*16 + koff];
    if (lg16 >= 2) Bq = zfrag;
    f32x4_t T[6];
    #pragma unroll
    for (int et = 0; et < 6; ++et) {
      bf16x8_t Aq = *(const bf16x8_t*)&qv[et*16 + ln16][h*16 + koff];
      if (lg16 >= 2) Aq = zfrag;
      T[et] = __builtin_amdgcn_mfma_f32_16x16x32_bf16(Aq, Bq, (f32x4_t)0.f, 0, 0, 0);
    }
    float mx = -1e30f;
    #pragma unroll
    for (int et = 0; et < 6; ++et)
      #pragma unroll
      for (int rg = 0; rg < 4; ++rg) {
        T[et][rg] *= 0.25f;
        mx = fmaxf(mx, T[et][rg]);
      }
    mx = fmaxf(mx, __shfl_xor(mx, 16));
    mx = fmaxf(mx, __shfl_xor(mx, 32));
    float tot = 0.f;
    #pragma unroll
    for (int et = 0; et < 6; ++et)
      #pragma unroll
      for (int rg = 0; rg < 4; ++rg) {
        float e = __expf(T[et][rg] - mx);
        T[et][rg] = e; tot += e;
      }
    tot += __shfl_xor(tot, 16);
    tot += __shfl_xor(tot, 32);
    float inv = 1.f / tot;
    #pragma unroll
    for (int et = 0; et < 6; ++et)
      #pragma unroll
      for (int rg = 0; rg < 4; ++rg)
        asumT[et][rg] += T[et][rg] * inv;
  }
  __syncthreads();   // all score reads of qu done before aliasing write

  // --- write asum[p][e] bf16 (aliased over qu) ---
  unsigned short (*asum)[104] = (unsigned short (*)[104])&qu[0][0];
  #pragma unroll
  for (int et = 0; et < 6; ++et) {
    ushort4 hv;
    hv.x = f2bf(asumT[et][0]); hv.y = f2bf(asumT[et][1]);
    hv.z = f2bf(asumT[et][2]); hv.w = f2bf(asumT[et][3]);
    *(ushort4*)&asum[w*16 + ln16][et*16 + lg16*4] = hv;
  }
  __syncthreads();

  // --- apply: m_t[p][d] = (1/8) sum_q asum[p][q] zn[q][d] via znT ---
  {
    bf16x8_t Aa[3];
    #pragma unroll
    for (int k = 0; k < 3; ++k)
      Aa[k] = *(const bf16x8_t*)&asum[prow][k*32 + lg16*8];
    #pragma unroll
    for (int dt = 0; dt < 8; ++dt) {
      f32x4_t acc = (f32x4_t)0.f;
      #pragma unroll
      for (int k = 0; k < 3; ++k) {
        bf16x8_t Bz = *(const bf16x8_t*)&znT[dt*16 + ln16][k*32 + lg16*8];
        acc = __builtin_amdgcn_mfma_f32_16x16x32_bf16(Aa[k], Bz, acc, 0, 0, 0);
      }
      #pragma unroll
      for (int rg = 0; rg < 4; ++rg)
        out[base + (size_t)(w*16 + lg16*4 + rg) * TD + dt*16 + ln16] = acc[rg] * 0.125f;
    }
  }
}

// ---------------------------------------------------------------------------
// K2: channel messages, full MFMA. One block per (b,p), 512 thr (8 waves).
// Wave w = c-tile. proj -> qu/qv; scores T[e][c] per head (K=16 zero-pad);
// softmax over e; asum mean_h * patch elementwise; += into out.
// ---------------------------------------------------------------------------
__global__ __launch_bounds__(512) void k_channel(
    const float* __restrict__ qz, const unsigned short* __restrict__ wCu,
    const unsigned short* __restrict__ wCv, const float* __restrict__ lng,
    const float* __restrict__ lnb, float* __restrict__ out)
{
  __shared__ unsigned short patch[128][136];
  __shared__ unsigned short qu  [128][136];
  __shared__ unsigned short qv  [128][136];

  const int tid = threadIdx.x;
  const int b = blockIdx.x / TP;
  const int p = blockIdx.x - b * TP;
  const size_t bbase = (size_t)b * (TC * TP * TD);

  // --- LN -> patch (bf16) ---
  {
    const int r = tid >> 2, sub = tid & 3;   // 128 rows x 4 lanes
    float x[32];
    float s = 0.f, s2 = 0.f;
    #pragma unroll
    for (int i = 0; i < 8; ++i) {
      float4 v = *(const float4*)(qz + bbase + ((size_t)r * TP + p) * TD + sub * 32 + i * 4);
      x[i*4+0] = v.x; x[i*4+1] = v.y; x[i*4+2] = v.z; x[i*4+3] = v.w;
      s += v.x + v.y + v.z + v.w;
      s2 += v.x*v.x + v.y*v.y + v.z*v.z + v.w*v.w;
    }
    s  += __shfl_xor(s, 1);  s  += __shfl_xor(s, 2);
    s2 += __shfl_xor(s2, 1); s2 += __shfl_xor(s2, 2);
    float mu = s * (1.f / 128.f);
    float rs = rsqrtf(s2 * (1.f / 128.f) - mu * mu + 1e-5f);
    #pragma unroll
    for (int j0 = 0; j0 < 32; j0 += 8) {
      u16x8_t v;
      #pragma unroll
      for (int j = 0; j < 8; ++j) {
        int d = sub * 32 + j0 + j;
        v[j] = f2bf((x[j0 + j] - mu) * rs * lng[d] + lnb[d]);
      }
      *(u16x8_t*)&patch[r][sub * 32 + j0] = v;
    }
  }
  __syncthreads();

  const int l = tid & 63, w = tid >> 6;      // w = c-tile 0..7
  const int ln16 = l & 15, lg16 = l >> 4;
  const int crow = w * 16 + ln16;

  // --- proj ---
  {
    bf16x8_t A[4];
    #pragma unroll
    for (int k = 0; k < 4; ++k)
      A[k] = *(const bf16x8_t*)&patch[crow][k*32 + lg16*8];
    #pragma unroll
    for (int m = 0; m < 2; ++m) {
      const unsigned short* W = ((m == 0) ? wCu : wCv) + (size_t)b * 16384;
      #pragma unroll
      for (int ot = 0; ot < 8; ++ot) {
        bf16x8_t Bf[4];
        #pragma unroll
        for (int k = 0; k < 4; ++k)
          Bf[k] = *(const bf16x8_t*)(W + (size_t)(ot*16 + ln16) * 128 + k*32 + lg16*8);
        f32x4_t acc = (f32x4_t)0.f;
        #pragma unroll
        for (int k = 0; k < 4; ++k)
          acc = __builtin_amdgcn_mfma_f32_16x16x32_bf16(A[k], Bf[k], acc, 0, 0, 0);
        unsigned short (*dst)[136] = (m == 0) ? qu : qv;
        #pragma unroll
        for (int rg = 0; rg < 4; ++rg)
          dst[w*16 + lg16*4 + rg][ot*16 + ln16] = f2bf(acc[rg]);
      }
    }
  }
  __syncthreads();

  // --- scores + softmax + head-sum ---
  f32x4_t asumT[8];
  #pragma unroll
  for (int et = 0; et < 8; ++et) asumT[et] = (f32x4_t)0.f;
  const bf16x8_t zfrag = (bf16x8_t)(short)0;
  const int koff = (lg16 & 1) * 8;
  for (int h = 0; h < TH; ++h) {
    bf16x8_t Bq = *(const bf16x8_t*)&qu[crow][h*16 + koff];
    if (lg16 >= 2) Bq = zfrag;
    f32x4_t T[8];
    #pragma unroll
    for (int et = 0; et < 8; ++et) {
      bf16x8_t Aq = *(const bf16x8_t*)&qv[et*16 + ln16][h*16 + koff];
      if (lg16 >= 2) Aq = zfrag;
      T[et] = __builtin_amdgcn_mfma_f32_16x16x32_bf16(Aq, Bq, (f32x4_t)0.f, 0, 0, 0);
    }
    float mx = -1e30f;
    #pragma unroll
    for (int et = 0; et < 8; ++et)
      #pragma unroll
      for (int rg = 0; rg < 4; ++rg) {
        T[et][rg] *= 0.25f;
        mx = fmaxf(mx, T[et][rg]);
      }
    mx = fmaxf(mx, __shfl_xor(mx, 16));
    mx = fmaxf(mx, __shfl_xor(mx, 32));
    float tot = 0.f;
    #pragma unroll
    for (int et = 0; et < 8; ++et)
      #pragma unroll
      for (int rg = 0; rg < 4; ++rg) {
        float e = __expf(T[et][rg] - mx);
        T[et][rg] = e; tot += e;
      }
    tot += __shfl_xor(tot, 16);
    tot += __shfl_xor(tot, 32);
    float inv = 1.f / tot;
    #pragma unroll
    for (int et = 0; et < 8; ++et)
      #pragma unroll
      for (int rg = 0; rg < 4; ++rg)
        asumT[et][rg] += T[et][rg] * inv;
  }

  // --- finish: out[c][f] += mean_h(attn)[c][f] * patch[c][f] ---
  {
    float* oa = out + bbase + ((size_t)crow * TP + p) * TD;
    #pragma unroll
    for (int et = 0; et < 8; ++et) {
      int f0 = et*16 + lg16*4;
      ushort4 ph = *(const ushort4*)&patch[crow][f0];
      float4 o4 = *(float4*)(oa + f0);
      o4.x += asumT[et][0] * 0.125f * bf2f(ph.x);
      o4.y += asumT[et][1] * 0.125f * bf2f(ph.y);
      o4.z += asumT[et][2] * 0.125f * bf2f(ph.z);
      o4.w += asumT[et][3] * 0.125f * bf2f(ph.w);
      *(float4*)(oa + f0) = o4;
    }
  }
}

// ---------------------------------------------------------------------------
// K3: topic messages, bf16 MFMA (unchanged from round 4).
// ---------------------------------------------------------------------------
__global__ __launch_bounds__(512) void k_topic(
    const float* __restrict__ qz, const unsigned short* __restrict__ binB,
    const unsigned short* __restrict__ binT, const float* __restrict__ lng,
    const float* __restrict__ lnb, float* __restrict__ out)
{
  __shared__ unsigned short zn [128][136];
  __shared__ unsigned short bt [128][136];
  __shared__ unsigned short btT[128][136];
  __shared__ unsigned short qg [128][136];
  __shared__ float rsum[4][128];

  const int tid = threadIdx.x;
  const int b = blockIdx.x / 96;
  const size_t row0 = (size_t)blockIdx.x * 128;
  const unsigned short* binBb = binB + (size_t)b * (TG * TD);
  const unsigned short* binTb = binT + (size_t)b * (TD * TG);

  {
    const int r = tid >> 2, sub = tid & 3;
    float x[32];
    float s = 0.f, s2 = 0.f;
    #pragma unroll
    for (int i = 0; i < 8; ++i) {
      float4 v = *(const float4*)(qz + (row0 + r) * TD + sub * 32 + i * 4);
      x[i*4+0] = v.x; x[i*4+1] = v.y; x[i*4+2] = v.z; x[i*4+3] = v.w;
      s += v.x + v.y + v.z + v.w;
      s2 += v.x*v.x + v.y*v.y + v.z*v.z + v.w*v.w;
    }
    s  += __shfl_xor(s, 1);  s  += __shfl_xor(s, 2);
    s2 += __shfl_xor(s2, 1); s2 += __shfl_xor(s2, 2);
    float mu = s * (1.f / 128.f);
    float rs = rsqrtf(s2 * (1.f / 128.f) - mu * mu + 1e-5f);
    #pragma unroll
    for (int j0 = 0; j0 < 32; j0 += 8) {
      u16x8_t v;
      #pragma unroll
      for (int j = 0; j < 8; ++j) {
        int d = sub * 32 + j0 + j;
        v[j] = f2bf((x[j0+j] - mu) * rs * lng[d] + lnb[d]);
      }
      *(u16x8_t*)&zn[r][sub * 32 + j0] = v;
    }
  }

  const int l = tid & 63;
  const int w = tid >> 6;
  const int wr = w >> 2;
  const int wc = w & 3;
  const int ln16 = l & 15, lg16 = l >> 4;

  f32x4_t macc[4][2];
  #pragma unroll
  for (int mi = 0; mi < 4; ++mi)
    #pragma unroll
    for (int ni = 0; ni < 2; ++ni) macc[mi][ni] = (f32x4_t)0.f;
  float rs_acc[4][4];
  #pragma unroll
  for (int mi = 0; mi < 4; ++mi)
    #pragma unroll
    for (int rg = 0; rg < 4; ++rg) rs_acc[mi][rg] = 0.f;

  for (int gt = 0; gt < 4; ++gt) {
    if (gt) __syncthreads();
    {
      const int row = tid >> 2, seg = tid & 3;
      const unsigned short* gsrc = binBb + (size_t)(gt * 128 + row) * TD + seg * 32;
      #pragma unroll
      for (int i = 0; i < 4; ++i)
        *(u16x8_t*)&bt[row][seg * 32 + i * 8] = *(const u16x8_t*)(gsrc + i * 8);
      const unsigned short* tsrc = binTb + (size_t)row * TG + gt * 128 + seg * 32;
      #pragma unroll
      for (int i = 0; i < 4; ++i)
        *(u16x8_t*)&btT[row][seg * 32 + i * 8] = *(const u16x8_t*)(tsrc + i * 8);
    }
    __syncthreads();

    {
      bf16x8_t B1[2][4];
      #pragma unroll
      for (int ni = 0; ni < 2; ++ni)
        #pragma unroll
        for (int k = 0; k < 4; ++k)
          B1[ni][k] = *(const bf16x8_t*)&bt[wc*32 + ni*16 + ln16][k*32 + lg16*8];
      #pragma unroll
      for (int mi = 0; mi < 4; ++mi) {
        const int r0 = wr*64 + mi*16;
        bf16x8_t A[4];
        #pragma unroll
        for (int k = 0; k < 4; ++k)
          A[k] = *(const bf16x8_t*)&zn[r0 + ln16][k*32 + lg16*8];
        #pragma unroll
        for (int ni = 0; ni < 2; ++ni) {
          f32x4_t acc = (f32x4_t)0.f;
          #pragma unroll
          for (int k = 0; k < 4; ++k)
            acc = __builtin_amdgcn_mfma_f32_16x16x32_bf16(A[k], B1[ni][k], acc, 0, 0, 0);
          #pragma unroll
          for (int rg = 0; rg < 4; ++rg) {
            float v = fmaxf(acc[rg], 0.f);
            rs_acc[mi][rg] += v;
            qg[r0 + lg16*4 + rg][wc*32 + ni*16 + ln16] = f2bf(v);
          }
        }
      }
    }
    __syncthreads();

    {
      bf16x8_t B2[2][4];
      #pragma unroll
      for (int ni = 0; ni < 2; ++ni)
        #pragma unroll
        for (int k = 0; k < 4; ++k)
          B2[ni][k] = *(const bf16x8_t*)&btT[wc*32 + ni*16 + ln16][k*32 + lg16*8];
      #pragma unroll
      for (int mi = 0; mi < 4; ++mi) {
        const int r0 = wr*64 + mi*16;
        bf16x8_t A2[4];
        #pragma unroll
        for (int k = 0; k < 4; ++k)
          A2[k] = *(const bf16x8_t*)&qg[r0 + ln16][k*32 + lg16*8];
        #pragma unroll
        for (int ni = 0; ni < 2; ++ni)
          #pragma unroll
          for (int k = 0; k < 4; ++k)
            macc[mi][ni] = __builtin_amdgcn_mfma_f32_16x16x32_bf16(A2[k], B2[ni][k], macc[mi][ni], 0, 0, 0);
      }
    }
  }

  #pragma unroll
  for (int mi = 0; mi < 4; ++mi)
    #pragma unroll
    for (int rg = 0; rg < 4; ++rg) {
      float s = rs_acc[mi][rg];
      s += __shfl_xor(s, 1); s += __shfl_xor(s, 2);
      s += __shfl_xor(s, 4); s += __shfl_xor(s, 8);
      rs_acc[mi][rg] = s;
    }
  if (ln16 == 0) {
    #pragma unroll
    for (int mi = 0; mi < 4; ++mi)
      #pragma unroll
      for (int rg = 0; rg < 4; ++rg)
        rsum[wc][wr*64 + mi*16 + lg16*4 + rg] = rs_acc[mi][rg];
  }
  __syncthreads();

  #pragma unroll
  for (int mi = 0; mi < 4; ++mi) {
    #pragma unroll
    for (int rg = 0; rg < 4; ++rg) {
      const int r = wr*64 + mi*16 + lg16*4 + rg;
      float tot = rsum[0][r] + rsum[1][r] + rsum[2][r] + rsum[3][r];
      float inv = 1.f / fmaxf(tot, 1e-6f);
      #pragma unroll
      for (int ni = 0; ni < 2; ++ni) {
        int d = wc*32 + ni*16 + ln16;
        out[(row0 + r) * TD + d] += macc[mi][ni][rg] * inv;
      }
    }
  }
}

// ---------------------------------------------------------------------------
// K4: combine + MLP (fp32, unchanged). One block per 64 rows.
// ---------------------------------------------------------------------------
__global__ __launch_bounds__(256) void k_final(
    const float* __restrict__ qz, const float* __restrict__ unary,
    const float* __restrict__ lng, const float* __restrict__ lnb,
    const float* __restrict__ w1, const float* __restrict__ b1,
    const float* __restrict__ w2, const float* __restrict__ b2,
    float* __restrict__ out)
{
  __shared__ float zmid[64][132];
  __shared__ float hbuf[64][132];
  __shared__ float wbuf[128][132];

  const int tid = threadIdx.x;
  const size_t row0 = (size_t)blockIdx.x * 64;

  #pragma unroll
  for (int i = 0; i < 8; ++i) {
    int idx4 = tid + i * 256;
    int r = idx4 >> 5;
    int d0 = (idx4 & 31) << 2;
    size_t a = (row0 + r) * TD + d0;
    float4 u4 = *(const float4*)(unary + a);
    float4 q4 = *(const float4*)(qz + a);
    float4 m4 = *(const float4*)(out + a);
    float4 z;
    z.x = 0.5f * (u4.x + m4.x + q4.x);
    z.y = 0.5f * (u4.y + m4.y + q4.y);
    z.z = 0.5f * (u4.z + m4.z + q4.z);
    z.w = 0.5f * (u4.w + m4.w + q4.w);
    *(float4*)&zmid[r][d0] = z;
  }
  __syncthreads();
  ln_rows<64>(zmid, hbuf, tid, lng, lnb);
  #pragma unroll
  for (int i = 0; i < 16; ++i) {
    int idx4 = tid + i * 256;
    int o = idx4 >> 5;
    int d0 = (idx4 & 31) << 2;
    *(float4*)&wbuf[o][d0] = *(const float4*)(w1 + (size_t)o * TD + d0);
  }
  __syncthreads();

  const int og = tid & 31, rg = tid >> 5;
  const int r0 = rg * 8;
  float acc[8][4];
  #pragma unroll
  for (int i = 0; i < 8; ++i)
    #pragma unroll
    for (int j = 0; j < 4; ++j) acc[i][j] = 0.f;
  for (int d4 = 0; d4 < TD; d4 += 4) {
    float4 a[8];
    #pragma unroll
    for (int i = 0; i < 8; ++i) a[i] = *(const float4*)&hbuf[r0 + i][d4];
    #pragma unroll
    for (int j = 0; j < 4; ++j) {
      float4 w = *(const float4*)&wbuf[og + 32 * j][d4];
      #pragma unroll
      for (int i = 0; i < 8; ++i) acc[i][j] += DOT4(a[i], w);
    }
  }
  float gel[8][4];
  #pragma unroll
  for (int j = 0; j < 4; ++j) {
    float bj = b1[og + 32 * j];
    #pragma unroll
    for (int i = 0; i < 8; ++i) {
      float x = acc[i][j] + bj;
      gel[i][j] = 0.5f * x * (1.f + erff(x * 0.70710678118654752f));
    }
  }
  __syncthreads();
  #pragma unroll
  for (int i = 0; i < 8; ++i)
    #pragma unroll
    for (int j = 0; j < 4; ++j) hbuf[r0 + i][og + 32 * j] = gel[i][j];
  #pragma unroll
  for (int i = 0; i < 16; ++i) {
    int idx4 = tid + i * 256;
    int o = idx4 >> 5;
    int d0 = (idx4 & 31) << 2;
    *(float4*)&wbuf[o][d0] = *(const float4*)(w2 + (size_t)o * TD + d0);
  }
  __syncthreads();

  float acc2[8][4];
  #pragma unroll
  for (int i = 0; i < 8; ++i)
    #pragma unroll
    for (int j = 0; j < 4; ++j) acc2[i][j] = 0.f;
  for (int d4 = 0; d4 < TD; d4 += 4) {
    float4 a[8];
    #pragma unroll
    for (int i = 0; i < 8; ++i) a[i] = *(const float4*)&hbuf[r0 + i][d4];
    #pragma unroll
    for (int j = 0; j < 4; ++j) {
      float4 w = *(const float4*)&wbuf[og + 32 * j][d4];
      #pragma unroll
      for (int i = 0; i < 8; ++i) acc2[i][j] += DOT4(a[i], w);
    }
  }
  #pragma unroll
  for (int j = 0; j < 4; ++j) {
    int o = og + 32 * j;
    float bj = b2[o];
    #pragma unroll
    for (int i = 0; i < 8; ++i) {
      out[(row0 + r0 + i) * TD + o] = zmid[r0 + i][o] + acc2[i][j] + bj;
    }
  }
}

// ---------------------------------------------------------------------------
extern "C" void kernel_launch(void* const* d_in, const int* in_sizes, int n_in,
                              void* d_out, int out_size, void* d_ws, size_t ws_size,
                              hipStream_t stream) {
  (void)in_sizes; (void)n_in; (void)out_size; (void)ws_size;
  const float* qz      = (const float*)d_in[0];
  const float* unary   = (const float*)d_in[1];
  const float* time_u  = (const float*)d_in[2];
  const float* time_v  = (const float*)d_in[3];
  const float* chan_u  = (const float*)d_in[4];
  const float* chan_v  = (const float*)d_in[5];
  const float* topic   = (const float*)d_in[6];
  const float* ln_g    = (const float*)d_in[7];
  const float* ln_b    = (const float*)d_in[8];
  const float* w1      = (const float*)d_in[9];
  const float* b1      = (const float*)d_in[10];
  const float* w2      = (const float*)d_in[11];
  const float* b2      = (const float*)d_in[12];
  float* out = (float*)d_out;

  unsigned short* binB = (unsigned short*)d_ws;           // 8*512*128
  unsigned short* binT = binB + (size_t)524288;           // 8*128*512
  unsigned short* wTu  = binT + (size_t)524288;           // 8*128*128
  unsigned short* wTv  = wTu + (size_t)131072;
  unsigned short* wCu  = wTv + (size_t)131072;
  unsigned short* wCv  = wCu + (size_t)131072;

  k_prep   <<<dim3(64), dim3(256), 0, stream>>>(topic, binB, binT);
  k_prepw  <<<dim3(512), dim3(256), 0, stream>>>(time_u, time_v, chan_u, chan_v,
                                                 wTu, wTv, wCu, wCv);
  k_time   <<<dim3(TB * TC), dim3(384), 0, stream>>>(qz, wTu, wTv, ln_g, ln_b, out);
  k_channel<<<dim3(TB * TP), dim3(512), 0, stream>>>(qz, wCu, wCv, ln_g, ln_b, out);
  k_topic  <<<dim3(TB * 96), dim3(512), 0, stream>>>(qz, binB, binT, ln_g, ln_b, out);
  k_final  <<<dim3(1536), dim3(256), 0, stream>>>(qz, unary, ln_g, ln_b, w1, b1, w2, b2, out);
}

// Round 6
// 479.990 us; speedup vs baseline: 2.9954x; 1.2367x over previous
//
#include <hip/hip_runtime.h>
#include <math.h>

#define TB 8
#define TC 128
#define TP 96
#define TD 128
#define TH 8
#define TG 512

typedef __attribute__((ext_vector_type(8))) short  bf16x8_t;
typedef __attribute__((ext_vector_type(8))) unsigned short u16x8_t;
typedef __attribute__((ext_vector_type(4))) float  f32x4_t;

__device__ __forceinline__ unsigned short f2bf(float f) {
  unsigned u = __float_as_uint(f);
  unsigned r = (u + 0x7fffu + ((u >> 16) & 1u)) >> 16;
  return (unsigned short)r;
}
__device__ __forceinline__ float bf2f(unsigned short h) {
  return __uint_as_float((unsigned)h << 16);
}

// ---------------------------------------------------------------------------
// K0a: prep — convert topic_binary to bf16 in both layouts.
// ---------------------------------------------------------------------------
__global__ __launch_bounds__(256) void k_prep(
    const float* __restrict__ bin, unsigned short* __restrict__ binB,
    unsigned short* __restrict__ binT)
{
  __shared__ unsigned short tile[64][132];
  const int tid = threadIdx.x;
  const int b = blockIdx.x >> 3;
  const int g0 = (blockIdx.x & 7) * 64;
  const size_t bb = (size_t)b * (TG * TD);

  #pragma unroll
  for (int i = 0; i < 8; ++i) {
    int idx4 = tid + i * 256;
    int g = idx4 >> 5;
    int d0 = (idx4 & 31) << 2;
    float4 v = *(const float4*)(bin + bb + (size_t)(g0 + g) * TD + d0);
    ushort4 h;
    h.x = f2bf(v.x); h.y = f2bf(v.y); h.z = f2bf(v.z); h.w = f2bf(v.w);
    *(ushort4*)(binB + bb + (size_t)(g0 + g) * TD + d0) = h;
    tile[g][d0] = h.x; tile[g][d0+1] = h.y; tile[g][d0+2] = h.z; tile[g][d0+3] = h.w;
  }
  __syncthreads();
  const int d = tid >> 1, half = tid & 1;
  unsigned short* dst = binT + (size_t)b * (TD * TG) + (size_t)d * TG + g0 + half * 32;
  #pragma unroll
  for (int i = 0; i < 8; ++i) {
    ushort4 o;
    o.x = tile[half*32 + 4*i + 0][d];
    o.y = tile[half*32 + 4*i + 1][d];
    o.z = tile[half*32 + 4*i + 2][d];
    o.w = tile[half*32 + 4*i + 3][d];
    *(ushort4*)(dst + 4*i) = o;
  }
}

// ---------------------------------------------------------------------------
// K0b: prep — convert attention weights (per-batch) and w1/w2 to bf16.
// blocks 0..511: 4 batch mats; blocks 512..543: w1,w2 (16 blocks each).
// ---------------------------------------------------------------------------
__global__ __launch_bounds__(256) void k_prepw(
    const float* __restrict__ tu, const float* __restrict__ tv,
    const float* __restrict__ cu, const float* __restrict__ cv,
    const float* __restrict__ w1, const float* __restrict__ w2,
    unsigned short* __restrict__ wTu, unsigned short* __restrict__ wTv,
    unsigned short* __restrict__ wCu, unsigned short* __restrict__ wCv,
    unsigned short* __restrict__ wW1, unsigned short* __restrict__ wW2)
{
  const int bid = blockIdx.x;
  const float* src; unsigned short* dst; size_t off;
  if (bid < 512) {
    const int m = bid >> 7;
    off = (size_t)(bid & 127) * 1024 + threadIdx.x * 4;
    src = (m == 0) ? tu : (m == 1) ? tv : (m == 2) ? cu : cv;
    dst = (m == 0) ? wTu : (m == 1) ? wTv : (m == 2) ? wCu : wCv;
  } else {
    const int t = bid - 512;
    const int m = t >> 4;
    off = (size_t)(t & 15) * 1024 + threadIdx.x * 4;
    src = m ? w2 : w1;
    dst = m ? wW2 : wW1;
  }
  float4 v = *(const float4*)(src + off);
  ushort4 h;
  h.x = f2bf(v.x); h.y = f2bf(v.y); h.z = f2bf(v.z); h.w = f2bf(v.w);
  *(ushort4*)(dst + off) = h;
}

// ---------------------------------------------------------------------------
// K1: time messages, full MFMA. One block per (b,c), 384 thr (6 waves).
// ---------------------------------------------------------------------------
__global__ __launch_bounds__(384) void k_time(
    const float* __restrict__ qz, const unsigned short* __restrict__ wTu,
    const unsigned short* __restrict__ wTv, const float* __restrict__ lng,
    const float* __restrict__ lnb, float* __restrict__ out)
{
  __shared__ unsigned short zn [96][136];
  __shared__ unsigned short znT[128][104];
  __shared__ unsigned short qu [96][136];
  __shared__ unsigned short qv [96][136];

  const int tid = threadIdx.x;
  const int b = blockIdx.x >> 7;
  const int c = blockIdx.x & 127;
  const size_t base = (size_t)(b * TC + c) * (TP * TD);

  // --- LN -> zn (bf16) + znT (bf16, transposed) ---
  {
    const int r = tid >> 2, sub = tid & 3;
    float x[32];
    float s = 0.f, s2 = 0.f;
    #pragma unroll
    for (int i = 0; i < 8; ++i) {
      float4 v = *(const float4*)(qz + base + (size_t)r * TD + sub * 32 + i * 4);
      x[i*4+0] = v.x; x[i*4+1] = v.y; x[i*4+2] = v.z; x[i*4+3] = v.w;
      s += v.x + v.y + v.z + v.w;
      s2 += v.x*v.x + v.y*v.y + v.z*v.z + v.w*v.w;
    }
    s  += __shfl_xor(s, 1);  s  += __shfl_xor(s, 2);
    s2 += __shfl_xor(s2, 1); s2 += __shfl_xor(s2, 2);
    float mu = s * (1.f / 128.f);
    float rs = rsqrtf(s2 * (1.f / 128.f) - mu * mu + 1e-5f);
    unsigned short hv[32];
    #pragma unroll
    for (int j = 0; j < 32; ++j) {
      int d = sub * 32 + j;
      hv[j] = f2bf((x[j] - mu) * rs * lng[d] + lnb[d]);
    }
    #pragma unroll
    for (int j0 = 0; j0 < 32; j0 += 8) {
      u16x8_t v;
      #pragma unroll
      for (int j = 0; j < 8; ++j) v[j] = hv[j0 + j];
      *(u16x8_t*)&zn[r][sub * 32 + j0] = v;
    }
    #pragma unroll
    for (int j = 0; j < 32; ++j) znT[sub * 32 + j][r] = hv[j];
  }
  __syncthreads();

  const int l = tid & 63, w = tid >> 6;
  const int ln16 = l & 15, lg16 = l >> 4;
  const int prow = w * 16 + ln16;

  // --- proj ---
  {
    bf16x8_t A[4];
    #pragma unroll
    for (int k = 0; k < 4; ++k)
      A[k] = *(const bf16x8_t*)&zn[prow][k*32 + lg16*8];
    #pragma unroll
    for (int m = 0; m < 2; ++m) {
      const unsigned short* W = ((m == 0) ? wTu : wTv) + (size_t)b * 16384;
      #pragma unroll
      for (int ot = 0; ot < 8; ++ot) {
        bf16x8_t Bf[4];
        #pragma unroll
        for (int k = 0; k < 4; ++k)
          Bf[k] = *(const bf16x8_t*)(W + (size_t)(ot*16 + ln16) * 128 + k*32 + lg16*8);
        f32x4_t acc = (f32x4_t)0.f;
        #pragma unroll
        for (int k = 0; k < 4; ++k)
          acc = __builtin_amdgcn_mfma_f32_16x16x32_bf16(A[k], Bf[k], acc, 0, 0, 0);
        unsigned short (*dst)[136] = (m == 0) ? qu : qv;
        #pragma unroll
        for (int rg = 0; rg < 4; ++rg)
          dst[w*16 + lg16*4 + rg][ot*16 + ln16] = f2bf(acc[rg]);
      }
    }
  }
  __syncthreads();

  // --- scores (transposed) + softmax over e + head-sum ---
  f32x4_t asumT[6];
  #pragma unroll
  for (int et = 0; et < 6; ++et) asumT[et] = (f32x4_t)0.f;
  const bf16x8_t zfrag = (bf16x8_t)(short)0;
  const int koff = (lg16 & 1) * 8;
  for (int h = 0; h < TH; ++h) {
    bf16x8_t Bq = *(const bf16x8_t*)&qu[prow][h*16 + koff];
    if (lg16 >= 2) Bq = zfrag;
    f32x4_t T[6];
    #pragma unroll
    for (int et = 0; et < 6; ++et) {
      bf16x8_t Aq = *(const bf16x8_t*)&qv[et*16 + ln16][h*16 + koff];
      if (lg16 >= 2) Aq = zfrag;
      T[et] = __builtin_amdgcn_mfma_f32_16x16x32_bf16(Aq, Bq, (f32x4_t)0.f, 0, 0, 0);
    }
    float mx = -1e30f;
    #pragma unroll
    for (int et = 0; et < 6; ++et)
      #pragma unroll
      for (int rg = 0; rg < 4; ++rg) {
        T[et][rg] *= 0.25f;
        mx = fmaxf(mx, T[et][rg]);
      }
    mx = fmaxf(mx, __shfl_xor(mx, 16));
    mx = fmaxf(mx, __shfl_xor(mx, 32));
    float tot = 0.f;
    #pragma unroll
    for (int et = 0; et < 6; ++et)
      #pragma unroll
      for (int rg = 0; rg < 4; ++rg) {
        float e = __expf(T[et][rg] - mx);
        T[et][rg] = e; tot += e;
      }
    tot += __shfl_xor(tot, 16);
    tot += __shfl_xor(tot, 32);
    float inv = 1.f / tot;
    #pragma unroll
    for (int et = 0; et < 6; ++et)
      #pragma unroll
      for (int rg = 0; rg < 4; ++rg)
        asumT[et][rg] += T[et][rg] * inv;
  }
  __syncthreads();

  unsigned short (*asum)[104] = (unsigned short (*)[104])&qu[0][0];
  #pragma unroll
  for (int et = 0; et < 6; ++et) {
    ushort4 hv;
    hv.x = f2bf(asumT[et][0]); hv.y = f2bf(asumT[et][1]);
    hv.z = f2bf(asumT[et][2]); hv.w = f2bf(asumT[et][3]);
    *(ushort4*)&asum[w*16 + ln16][et*16 + lg16*4] = hv;
  }
  __syncthreads();

  // --- apply ---
  {
    bf16x8_t Aa[3];
    #pragma unroll
    for (int k = 0; k < 3; ++k)
      Aa[k] = *(const bf16x8_t*)&asum[prow][k*32 + lg16*8];
    #pragma unroll
    for (int dt = 0; dt < 8; ++dt) {
      f32x4_t acc = (f32x4_t)0.f;
      #pragma unroll
      for (int k = 0; k < 3; ++k) {
        bf16x8_t Bz = *(const bf16x8_t*)&znT[dt*16 + ln16][k*32 + lg16*8];
        acc = __builtin_amdgcn_mfma_f32_16x16x32_bf16(Aa[k], Bz, acc, 0, 0, 0);
      }
      #pragma unroll
      for (int rg = 0; rg < 4; ++rg)
        out[base + (size_t)(w*16 + lg16*4 + rg) * TD + dt*16 + ln16] = acc[rg] * 0.125f;
    }
  }
}

// ---------------------------------------------------------------------------
// K2: channel messages, full MFMA. One block per (b,p), 512 thr (8 waves).
// ---------------------------------------------------------------------------
__global__ __launch_bounds__(512) void k_channel(
    const float* __restrict__ qz, const unsigned short* __restrict__ wCu,
    const unsigned short* __restrict__ wCv, const float* __restrict__ lng,
    const float* __restrict__ lnb, float* __restrict__ out)
{
  __shared__ unsigned short patch[128][136];
  __shared__ unsigned short qu  [128][136];
  __shared__ unsigned short qv  [128][136];

  const int tid = threadIdx.x;
  const int b = blockIdx.x / TP;
  const int p = blockIdx.x - b * TP;
  const size_t bbase = (size_t)b * (TC * TP * TD);

  {
    const int r = tid >> 2, sub = tid & 3;
    float x[32];
    float s = 0.f, s2 = 0.f;
    #pragma unroll
    for (int i = 0; i < 8; ++i) {
      float4 v = *(const float4*)(qz + bbase + ((size_t)r * TP + p) * TD + sub * 32 + i * 4);
      x[i*4+0] = v.x; x[i*4+1] = v.y; x[i*4+2] = v.z; x[i*4+3] = v.w;
      s += v.x + v.y + v.z + v.w;
      s2 += v.x*v.x + v.y*v.y + v.z*v.z + v.w*v.w;
    }
    s  += __shfl_xor(s, 1);  s  += __shfl_xor(s, 2);
    s2 += __shfl_xor(s2, 1); s2 += __shfl_xor(s2, 2);
    float mu = s * (1.f / 128.f);
    float rs = rsqrtf(s2 * (1.f / 128.f) - mu * mu + 1e-5f);
    #pragma unroll
    for (int j0 = 0; j0 < 32; j0 += 8) {
      u16x8_t v;
      #pragma unroll
      for (int j = 0; j < 8; ++j) {
        int d = sub * 32 + j0 + j;
        v[j] = f2bf((x[j0 + j] - mu) * rs * lng[d] + lnb[d]);
      }
      *(u16x8_t*)&patch[r][sub * 32 + j0] = v;
    }
  }
  __syncthreads();

  const int l = tid & 63, w = tid >> 6;
  const int ln16 = l & 15, lg16 = l >> 4;
  const int crow = w * 16 + ln16;

  {
    bf16x8_t A[4];
    #pragma unroll
    for (int k = 0; k < 4; ++k)
      A[k] = *(const bf16x8_t*)&patch[crow][k*32 + lg16*8];
    #pragma unroll
    for (int m = 0; m < 2; ++m) {
      const unsigned short* W = ((m == 0) ? wCu : wCv) + (size_t)b * 16384;
      #pragma unroll
      for (int ot = 0; ot < 8; ++ot) {
        bf16x8_t Bf[4];
        #pragma unroll
        for (int k = 0; k < 4; ++k)
          Bf[k] = *(const bf16x8_t*)(W + (size_t)(ot*16 + ln16) * 128 + k*32 + lg16*8);
        f32x4_t acc = (f32x4_t)0.f;
        #pragma unroll
        for (int k = 0; k < 4; ++k)
          acc = __builtin_amdgcn_mfma_f32_16x16x32_bf16(A[k], Bf[k], acc, 0, 0, 0);
        unsigned short (*dst)[136] = (m == 0) ? qu : qv;
        #pragma unroll
        for (int rg = 0; rg < 4; ++rg)
          dst[w*16 + lg16*4 + rg][ot*16 + ln16] = f2bf(acc[rg]);
      }
    }
  }
  __syncthreads();

  f32x4_t asumT[8];
  #pragma unroll
  for (int et = 0; et < 8; ++et) asumT[et] = (f32x4_t)0.f;
  const bf16x8_t zfrag = (bf16x8_t)(short)0;
  const int koff = (lg16 & 1) * 8;
  for (int h = 0; h < TH; ++h) {
    bf16x8_t Bq = *(const bf16x8_t*)&qu[crow][h*16 + koff];
    if (lg16 >= 2) Bq = zfrag;
    f32x4_t T[8];
    #pragma unroll
    for (int et = 0; et < 8; ++et) {
      bf16x8_t Aq = *(const bf16x8_t*)&qv[et*16 + ln16][h*16 + koff];
      if (lg16 >= 2) Aq = zfrag;
      T[et] = __builtin_amdgcn_mfma_f32_16x16x32_bf16(Aq, Bq, (f32x4_t)0.f, 0, 0, 0);
    }
    float mx = -1e30f;
    #pragma unroll
    for (int et = 0; et < 8; ++et)
      #pragma unroll
      for (int rg = 0; rg < 4; ++rg) {
        T[et][rg] *= 0.25f;
        mx = fmaxf(mx, T[et][rg]);
      }
    mx = fmaxf(mx, __shfl_xor(mx, 16));
    mx = fmaxf(mx, __shfl_xor(mx, 32));
    float tot = 0.f;
    #pragma unroll
    for (int et = 0; et < 8; ++et)
      #pragma unroll
      for (int rg = 0; rg < 4; ++rg) {
        float e = __expf(T[et][rg] - mx);
        T[et][rg] = e; tot += e;
      }
    tot += __shfl_xor(tot, 16);
    tot += __shfl_xor(tot, 32);
    float inv = 1.f / tot;
    #pragma unroll
    for (int et = 0; et < 8; ++et)
      #pragma unroll
      for (int rg = 0; rg < 4; ++rg)
        asumT[et][rg] += T[et][rg] * inv;
  }

  {
    float* oa = out + bbase + ((size_t)crow * TP + p) * TD;
    #pragma unroll
    for (int et = 0; et < 8; ++et) {
      int f0 = et*16 + lg16*4;
      ushort4 ph = *(const ushort4*)&patch[crow][f0];
      float4 o4 = *(float4*)(oa + f0);
      o4.x += asumT[et][0] * 0.125f * bf2f(ph.x);
      o4.y += asumT[et][1] * 0.125f * bf2f(ph.y);
      o4.z += asumT[et][2] * 0.125f * bf2f(ph.z);
      o4.w += asumT[et][3] * 0.125f * bf2f(ph.w);
      *(float4*)(oa + f0) = o4;
    }
  }
}

// ---------------------------------------------------------------------------
// K3: topic messages, bf16 MFMA (unchanged).
// ---------------------------------------------------------------------------
__global__ __launch_bounds__(512) void k_topic(
    const float* __restrict__ qz, const unsigned short* __restrict__ binB,
    const unsigned short* __restrict__ binT, const float* __restrict__ lng,
    const float* __restrict__ lnb, float* __restrict__ out)
{
  __shared__ unsigned short zn [128][136];
  __shared__ unsigned short bt [128][136];
  __shared__ unsigned short btT[128][136];
  __shared__ unsigned short qg [128][136];
  __shared__ float rsum[4][128];

  const int tid = threadIdx.x;
  const int b = blockIdx.x / 96;
  const size_t row0 = (size_t)blockIdx.x * 128;
  const unsigned short* binBb = binB + (size_t)b * (TG * TD);
  const unsigned short* binTb = binT + (size_t)b * (TD * TG);

  {
    const int r = tid >> 2, sub = tid & 3;
    float x[32];
    float s = 0.f, s2 = 0.f;
    #pragma unroll
    for (int i = 0; i < 8; ++i) {
      float4 v = *(const float4*)(qz + (row0 + r) * TD + sub * 32 + i * 4);
      x[i*4+0] = v.x; x[i*4+1] = v.y; x[i*4+2] = v.z; x[i*4+3] = v.w;
      s += v.x + v.y + v.z + v.w;
      s2 += v.x*v.x + v.y*v.y + v.z*v.z + v.w*v.w;
    }
    s  += __shfl_xor(s, 1);  s  += __shfl_xor(s, 2);
    s2 += __shfl_xor(s2, 1); s2 += __shfl_xor(s2, 2);
    float mu = s * (1.f / 128.f);
    float rs = rsqrtf(s2 * (1.f / 128.f) - mu * mu + 1e-5f);
    #pragma unroll
    for (int j0 = 0; j0 < 32; j0 += 8) {
      u16x8_t v;
      #pragma unroll
      for (int j = 0; j < 8; ++j) {
        int d = sub * 32 + j0 + j;
        v[j] = f2bf((x[j0+j] - mu) * rs * lng[d] + lnb[d]);
      }
      *(u16x8_t*)&zn[r][sub * 32 + j0] = v;
    }
  }

  const int l = tid & 63;
  const int w = tid >> 6;
  const int wr = w >> 2;
  const int wc = w & 3;
  const int ln16 = l & 15, lg16 = l >> 4;

  f32x4_t macc[4][2];
  #pragma unroll
  for (int mi = 0; mi < 4; ++mi)
    #pragma unroll
    for (int ni = 0; ni < 2; ++ni) macc[mi][ni] = (f32x4_t)0.f;
  float rs_acc[4][4];
  #pragma unroll
  for (int mi = 0; mi < 4; ++mi)
    #pragma unroll
    for (int rg = 0; rg < 4; ++rg) rs_acc[mi][rg] = 0.f;

  for (int gt = 0; gt < 4; ++gt) {
    if (gt) __syncthreads();
    {
      const int row = tid >> 2, seg = tid & 3;
      const unsigned short* gsrc = binBb + (size_t)(gt * 128 + row) * TD + seg * 32;
      #pragma unroll
      for (int i = 0; i < 4; ++i)
        *(u16x8_t*)&bt[row][seg * 32 + i * 8] = *(const u16x8_t*)(gsrc + i * 8);
      const unsigned short* tsrc = binTb + (size_t)row * TG + gt * 128 + seg * 32;
      #pragma unroll
      for (int i = 0; i < 4; ++i)
        *(u16x8_t*)&btT[row][seg * 32 + i * 8] = *(const u16x8_t*)(tsrc + i * 8);
    }
    __syncthreads();

    {
      bf16x8_t B1[2][4];
      #pragma unroll
      for (int ni = 0; ni < 2; ++ni)
        #pragma unroll
        for (int k = 0; k < 4; ++k)
          B1[ni][k] = *(const bf16x8_t*)&bt[wc*32 + ni*16 + ln16][k*32 + lg16*8];
      #pragma unroll
      for (int mi = 0; mi < 4; ++mi) {
        const int r0 = wr*64 + mi*16;
        bf16x8_t A[4];
        #pragma unroll
        for (int k = 0; k < 4; ++k)
          A[k] = *(const bf16x8_t*)&zn[r0 + ln16][k*32 + lg16*8];
        #pragma unroll
        for (int ni = 0; ni < 2; ++ni) {
          f32x4_t acc = (f32x4_t)0.f;
          #pragma unroll
          for (int k = 0; k < 4; ++k)
            acc = __builtin_amdgcn_mfma_f32_16x16x32_bf16(A[k], B1[ni][k], acc, 0, 0, 0);
          #pragma unroll
          for (int rg = 0; rg < 4; ++rg) {
            float v = fmaxf(acc[rg], 0.f);
            rs_acc[mi][rg] += v;
            qg[r0 + lg16*4 + rg][wc*32 + ni*16 + ln16] = f2bf(v);
          }
        }
      }
    }
    __syncthreads();

    {
      bf16x8_t B2[2][4];
      #pragma unroll
      for (int ni = 0; ni < 2; ++ni)
        #pragma unroll
        for (int k = 0; k < 4; ++k)
          B2[ni][k] = *(const bf16x8_t*)&btT[wc*32 + ni*16 + ln16][k*32 + lg16*8];
      #pragma unroll
      for (int mi = 0; mi < 4; ++mi) {
        const int r0 = wr*64 + mi*16;
        bf16x8_t A2[4];
        #pragma unroll
        for (int k = 0; k < 4; ++k)
          A2[k] = *(const bf16x8_t*)&qg[r0 + ln16][k*32 + lg16*8];
        #pragma unroll
        for (int ni = 0; ni < 2; ++ni)
          #pragma unroll
          for (int k = 0; k < 4; ++k)
            macc[mi][ni] = __builtin_amdgcn_mfma_f32_16x16x32_bf16(A2[k], B2[ni][k], macc[mi][ni], 0, 0, 0);
      }
    }
  }

  #pragma unroll
  for (int mi = 0; mi < 4; ++mi)
    #pragma unroll
    for (int rg = 0; rg < 4; ++rg) {
      float s = rs_acc[mi][rg];
      s += __shfl_xor(s, 1); s += __shfl_xor(s, 2);
      s += __shfl_xor(s, 4); s += __shfl_xor(s, 8);
      rs_acc[mi][rg] = s;
    }
  if (ln16 == 0) {
    #pragma unroll
    for (int mi = 0; mi < 4; ++mi)
      #pragma unroll
      for (int rg = 0; rg < 4; ++rg)
        rsum[wc][wr*64 + mi*16 + lg16*4 + rg] = rs_acc[mi][rg];
  }
  __syncthreads();

  #pragma unroll
  for (int mi = 0; mi < 4; ++mi) {
    #pragma unroll
    for (int rg = 0; rg < 4; ++rg) {
      const int r = wr*64 + mi*16 + lg16*4 + rg;
      float tot = rsum[0][r] + rsum[1][r] + rsum[2][r] + rsum[3][r];
      float inv = 1.f / fmaxf(tot, 1e-6f);
      #pragma unroll
      for (int ni = 0; ni < 2; ++ni) {
        int d = wc*32 + ni*16 + ln16;
        out[(row0 + r) * TD + d] += macc[mi][ni][rg] * inv;
      }
    }
  }
}

// ---------------------------------------------------------------------------
// K4: combine + MLP, bf16 MFMA. One block per 128 rows, 512 thr (8 waves).
// zmid fp32 in LDS (residual); hn/h2 bf16. Weights read from L2 (prepped bf16).
// ---------------------------------------------------------------------------
__global__ __launch_bounds__(512) void k_final(
    const float* __restrict__ qz, const float* __restrict__ unary,
    const float* __restrict__ lng, const float* __restrict__ lnb,
    const unsigned short* __restrict__ w1, const float* __restrict__ b1,
    const unsigned short* __restrict__ w2, const float* __restrict__ b2,
    float* __restrict__ out)
{
  __shared__ float zmid[128][132];
  __shared__ unsigned short hn[128][136];
  __shared__ unsigned short h2[128][136];

  const int tid = threadIdx.x;
  const size_t row0 = (size_t)blockIdx.x * 128;

  // --- combine + LN -> zmid (fp32) + hn (bf16) ---
  {
    const int r = tid >> 2, sub = tid & 3;
    const size_t rowa = (row0 + r) * TD + sub * 32;
    float x[32];
    float s = 0.f, s2 = 0.f;
    #pragma unroll
    for (int i = 0; i < 8; ++i) {
      float4 q4 = *(const float4*)(qz + rowa + i * 4);
      float4 u4 = *(const float4*)(unary + rowa + i * 4);
      float4 m4 = *(const float4*)(out + rowa + i * 4);
      float4 z;
      z.x = 0.5f * (u4.x + m4.x + q4.x);
      z.y = 0.5f * (u4.y + m4.y + q4.y);
      z.z = 0.5f * (u4.z + m4.z + q4.z);
      z.w = 0.5f * (u4.w + m4.w + q4.w);
      *(float4*)&zmid[r][sub * 32 + i * 4] = z;
      x[i*4+0] = z.x; x[i*4+1] = z.y; x[i*4+2] = z.z; x[i*4+3] = z.w;
      s += z.x + z.y + z.z + z.w;
      s2 += z.x*z.x + z.y*z.y + z.z*z.z + z.w*z.w;
    }
    s  += __shfl_xor(s, 1);  s  += __shfl_xor(s, 2);
    s2 += __shfl_xor(s2, 1); s2 += __shfl_xor(s2, 2);
    float mu = s * (1.f / 128.f);
    float rs = rsqrtf(s2 * (1.f / 128.f) - mu * mu + 1e-5f);
    #pragma unroll
    for (int j0 = 0; j0 < 32; j0 += 8) {
      u16x8_t v;
      #pragma unroll
      for (int j = 0; j < 8; ++j) {
        int d = sub * 32 + j0 + j;
        v[j] = f2bf((x[j0 + j] - mu) * rs * lng[d] + lnb[d]);
      }
      *(u16x8_t*)&hn[r][sub * 32 + j0] = v;
    }
  }
  __syncthreads();

  const int l = tid & 63, w = tid >> 6;
  const int wr = w >> 2, wc = w & 3;
  const int ln16 = l & 15, lg16 = l >> 4;
  const int bcol = wc * 32 + ln16;          // B-frag row / output col base (+16*ni)

  // --- GEMM1 + bias + gelu -> h2 ---
  {
    bf16x8_t Bf[2][4];
    float b1v[2];
    #pragma unroll
    for (int ni = 0; ni < 2; ++ni) {
      b1v[ni] = b1[bcol + ni * 16];
      #pragma unroll
      for (int k = 0; k < 4; ++k)
        Bf[ni][k] = *(const bf16x8_t*)(w1 + (size_t)(bcol + ni * 16) * 128 + k*32 + lg16*8);
    }
    #pragma unroll
    for (int mi = 0; mi < 4; ++mi) {
      const int r0 = wr * 64 + mi * 16;
      bf16x8_t A[4];
      #pragma unroll
      for (int k = 0; k < 4; ++k)
        A[k] = *(const bf16x8_t*)&hn[r0 + ln16][k*32 + lg16*8];
      #pragma unroll
      for (int ni = 0; ni < 2; ++ni) {
        f32x4_t acc = (f32x4_t)0.f;
        #pragma unroll
        for (int k = 0; k < 4; ++k)
          acc = __builtin_amdgcn_mfma_f32_16x16x32_bf16(A[k], Bf[ni][k], acc, 0, 0, 0);
        #pragma unroll
        for (int rg = 0; rg < 4; ++rg) {
          float xx = acc[rg] + b1v[ni];
          float g = 0.5f * xx * (1.f + erff(xx * 0.70710678118654752f));
          h2[r0 + lg16*4 + rg][bcol + ni * 16] = f2bf(g);
        }
      }
    }
  }
  __syncthreads();

  // --- GEMM2 + b2 + residual -> out ---
  {
    bf16x8_t Bf[2][4];
    float b2v[2];
    #pragma unroll
    for (int ni = 0; ni < 2; ++ni) {
      b2v[ni] = b2[bcol + ni * 16];
      #pragma unroll
      for (int k = 0; k < 4; ++k)
        Bf[ni][k] = *(const bf16x8_t*)(w2 + (size_t)(bcol + ni * 16) * 128 + k*32 + lg16*8);
    }
    #pragma unroll
    for (int mi = 0; mi < 4; ++mi) {
      const int r0 = wr * 64 + mi * 16;
      bf16x8_t A[4];
      #pragma unroll
      for (int k = 0; k < 4; ++k)
        A[k] = *(const bf16x8_t*)&h2[r0 + ln16][k*32 + lg16*8];
      #pragma unroll
      for (int ni = 0; ni < 2; ++ni) {
        f32x4_t acc = (f32x4_t)0.f;
        #pragma unroll
        for (int k = 0; k < 4; ++k)
          acc = __builtin_amdgcn_mfma_f32_16x16x32_bf16(A[k], Bf[ni][k], acc, 0, 0, 0);
        #pragma unroll
        for (int rg = 0; rg < 4; ++rg) {
          const int rr = r0 + lg16*4 + rg;
          const int cc = bcol + ni * 16;
          out[(row0 + rr) * TD + cc] = zmid[rr][cc] + acc[rg] + b2v[ni];
        }
      }
    }
  }
}

// ---------------------------------------------------------------------------
extern "C" void kernel_launch(void* const* d_in, const int* in_sizes, int n_in,
                              void* d_out, int out_size, void* d_ws, size_t ws_size,
                              hipStream_t stream) {
  (void)in_sizes; (void)n_in; (void)out_size; (void)ws_size;
  const float* qz      = (const float*)d_in[0];
  const float* unary   = (const float*)d_in[1];
  const float* time_u  = (const float*)d_in[2];
  const float* time_v  = (const float*)d_in[3];
  const float* chan_u  = (const float*)d_in[4];
  const float* chan_v  = (const float*)d_in[5];
  const float* topic   = (const float*)d_in[6];
  const float* ln_g    = (const float*)d_in[7];
  const float* ln_b    = (const float*)d_in[8];
  const float* w1      = (const float*)d_in[9];
  const float* b1      = (const float*)d_in[10];
  const float* w2      = (const float*)d_in[11];
  const float* b2      = (const float*)d_in[12];
  float* out = (float*)d_out;

  unsigned short* binB = (unsigned short*)d_ws;           // 8*512*128
  unsigned short* binT = binB + (size_t)524288;           // 8*128*512
  unsigned short* wTu  = binT + (size_t)524288;           // 8*128*128 each
  unsigned short* wTv  = wTu + (size_t)131072;
  unsigned short* wCu  = wTv + (size_t)131072;
  unsigned short* wCv  = wCu + (size_t)131072;
  unsigned short* wW1  = wCv + (size_t)131072;            // 128*128
  unsigned short* wW2  = wW1 + (size_t)16384;

  k_prep   <<<dim3(64), dim3(256), 0, stream>>>(topic, binB, binT);
  k_prepw  <<<dim3(544), dim3(256), 0, stream>>>(time_u, time_v, chan_u, chan_v, w1, w2,
                                                 wTu, wTv, wCu, wCv, wW1, wW2);
  k_time   <<<dim3(TB * TC), dim3(384), 0, stream>>>(qz, wTu, wTv, ln_g, ln_b, out);
  k_channel<<<dim3(TB * TP), dim3(512), 0, stream>>>(qz, wCu, wCv, ln_g, ln_b, out);
  k_topic  <<<dim3(TB * 96), dim3(512), 0, stream>>>(qz, binB, binT, ln_g, ln_b, out);
  k_final  <<<dim3(768), dim3(512), 0, stream>>>(qz, unary, ln_g, ln_b, wW1, b1, wW2, b2, out);
}